// Round 1
// baseline (1554.127 us; speedup 1.0000x reference)
//
#include <hip/hip_runtime.h>

#define HCDIM 292
#define NHEAD 4
#define CDIM 73
#define SLOTS 5
#define BN_EPS 1e-5f

// ======================= utility: zero fill =======================
__global__ void k_zero_i32(int* __restrict__ p, int n) {
  int i = blockIdx.x * blockDim.x + threadIdx.x;
  if (i < n) p[i] = 0;
}
__global__ void k_zero_f32(float* __restrict__ p, int n) {
  int i = blockIdx.x * blockDim.x + threadIdx.x;
  if (i < n) p[i] = 0.f;
}

// ======================= CSR build =======================
__global__ void k_hist(const int* __restrict__ dst, int* __restrict__ deg, int E) {
  int i = blockIdx.x * blockDim.x + threadIdx.x;
  if (i < E) atomicAdd(&deg[dst[i]], 1);
}

__global__ __launch_bounds__(256) void k_block_sum(const int* __restrict__ deg,
                                                   int* __restrict__ bsum, int n) {
  __shared__ int s[256];
  int i = blockIdx.x * 256 + threadIdx.x;
  s[threadIdx.x] = (i < n) ? deg[i] : 0;
  __syncthreads();
  for (int off = 128; off > 0; off >>= 1) {
    if (threadIdx.x < off) s[threadIdx.x] += s[threadIdx.x + off];
    __syncthreads();
  }
  if (threadIdx.x == 0) bsum[blockIdx.x] = s[0];
}

// exclusive scan of bsum[0..G) into boff[0..G), G <= 256, single block
__global__ __launch_bounds__(256) void k_scan_small(const int* __restrict__ bsum,
                                                    int* __restrict__ boff, int G) {
  __shared__ int s[256];
  int t = threadIdx.x;
  int v = (t < G) ? bsum[t] : 0;
  s[t] = v;
  __syncthreads();
  for (int off = 1; off < 256; off <<= 1) {
    int tv = (t >= off) ? s[t - off] : 0;
    __syncthreads();
    s[t] += tv;
    __syncthreads();
  }
  if (t < G) boff[t] = s[t] - v;  // exclusive
}

__global__ __launch_bounds__(256) void k_scan_final(const int* __restrict__ deg,
                                                    const int* __restrict__ boff,
                                                    int* __restrict__ row_ptr, int n) {
  __shared__ int s[256];
  int t = threadIdx.x;
  int i = blockIdx.x * 256 + t;
  int v = (i < n) ? deg[i] : 0;
  s[t] = v;
  __syncthreads();
  for (int off = 1; off < 256; off <<= 1) {
    int tv = (t >= off) ? s[t - off] : 0;
    __syncthreads();
    s[t] += tv;
    __syncthreads();
  }
  if (i < n) row_ptr[i] = boff[blockIdx.x] + s[t] - v;
}

__global__ void k_fill_cursor(int* __restrict__ row_ptr, int* __restrict__ cursor,
                              int n, int E) {
  int i = blockIdx.x * blockDim.x + threadIdx.x;
  if (i < n) cursor[i] = row_ptr[i];
  if (i == 0) row_ptr[n] = E;
}

__global__ void k_csr_fill(const int* __restrict__ srcs, const int* __restrict__ dsts,
                           int* __restrict__ cursor, int* __restrict__ csr_src, int E) {
  int i = blockIdx.x * blockDim.x + threadIdx.x;
  if (i < E) {
    int pos = atomicAdd(&cursor[dsts[i]], 1);
    csr_src[pos] = srcs[i];
  }
}

// ======================= GEMM: out[M,Nc] = A[M,K] @ W[Nc,K]^T + bias =======================
// 64x64 tile, BK=32, 256 threads, 4x4 microtile per thread.
#define GBM 64
#define GBN 64
#define GBK 32

__global__ __launch_bounds__(256) void k_gemm_nt(const float* __restrict__ A,
                                                 const float* __restrict__ W,
                                                 const float* __restrict__ bias,
                                                 float* __restrict__ out,
                                                 int M, int Nc, int K) {
  __shared__ float As[GBK][GBM + 4];  // [k][m], +4 pad keeps float4 alignment
  __shared__ float Bs[GBK][GBN + 4];  // [k][n]
  int bm = blockIdx.x * GBM;
  int bn = blockIdx.y * GBN;
  int tid = threadIdx.x;
  int tc = tid & 15;   // n-dir (x4)
  int tr = tid >> 4;   // m-dir (x4)
  float acc[4][4] = {};

  for (int k0 = 0; k0 < K; k0 += GBK) {
#pragma unroll
    for (int i = 0; i < 8; ++i) {
      int e = tid + 256 * i;
      int r = e >> 5, c = e & 31;
      int gm = bm + r, gk = k0 + c;
      As[c][r] = (gm < M && gk < K) ? A[(size_t)gm * K + gk] : 0.f;
    }
#pragma unroll
    for (int i = 0; i < 8; ++i) {
      int e = tid + 256 * i;
      int r = e >> 5, c = e & 31;
      int gn = bn + r, gk = k0 + c;
      Bs[c][r] = (gn < Nc && gk < K) ? W[(size_t)gn * K + gk] : 0.f;
    }
    __syncthreads();
#pragma unroll
    for (int kk = 0; kk < GBK; ++kk) {
      float4 av = *(const float4*)&As[kk][tr * 4];
      float4 bv = *(const float4*)&Bs[kk][tc * 4];
      acc[0][0] += av.x * bv.x; acc[0][1] += av.x * bv.y; acc[0][2] += av.x * bv.z; acc[0][3] += av.x * bv.w;
      acc[1][0] += av.y * bv.x; acc[1][1] += av.y * bv.y; acc[1][2] += av.y * bv.z; acc[1][3] += av.y * bv.w;
      acc[2][0] += av.z * bv.x; acc[2][1] += av.z * bv.y; acc[2][2] += av.z * bv.z; acc[2][3] += av.z * bv.w;
      acc[3][0] += av.w * bv.x; acc[3][1] += av.w * bv.y; acc[3][2] += av.w * bv.z; acc[3][3] += av.w * bv.w;
    }
    __syncthreads();
  }

#pragma unroll
  for (int i = 0; i < 4; ++i) {
    int gm = bm + tr * 4 + i;
    if (gm >= M) continue;
#pragma unroll
    for (int j = 0; j < 4; ++j) {
      int gn = bn + tc * 4 + j;
      if (gn < Nc) out[(size_t)gm * Nc + gn] = acc[i][j] + bias[gn];
    }
  }
}

// ======================= fused GATv2 attention + softmax + aggregate =======================
// one 64-lane wave per destination node; online softmax over incoming edges.
__global__ __launch_bounds__(256) void k_agg(const float* __restrict__ xl,
                                             const float* __restrict__ xr,
                                             const int* __restrict__ csr_src,
                                             const int* __restrict__ row_ptr,
                                             const float* __restrict__ att,
                                             const float* __restrict__ bvec,
                                             float* __restrict__ out, int n) {
  int wave = threadIdx.x >> 6;
  int lane = threadIdx.x & 63;
  int d = blockIdx.x * 4 + wave;
  if (d >= n) return;
  int start = row_ptr[d];
  int end = row_ptr[d + 1];

  float xrv[SLOTS], attv[SLOTS], acc[SLOTS];
  int hk[SLOTS];
#pragma unroll
  for (int k = 0; k < SLOTS; ++k) {
    int slot = lane + 64 * k;
    bool act = slot < HCDIM;
    xrv[k] = act ? xr[(size_t)d * HCDIM + slot] : 0.f;
    attv[k] = act ? att[slot] : 0.f;
    hk[k] = act ? (slot / CDIM) : 0;
    acc[k] = 0.f;
  }
  float m[NHEAD] = {-1e30f, -1e30f, -1e30f, -1e30f};
  float den[NHEAD] = {0.f, 0.f, 0.f, 0.f};

  for (int e = start; e < end; ++e) {
    int src = csr_src[e];
    float xlv[SLOTS];
    float hsum[NHEAD] = {0.f, 0.f, 0.f, 0.f};
#pragma unroll
    for (int k = 0; k < SLOTS; ++k) {
      int slot = lane + 64 * k;
      float v = (slot < HCDIM) ? xl[(size_t)src * HCDIM + slot] : 0.f;
      xlv[k] = v;
      float f = v + xrv[k];
      float lr = (f > 0.f) ? f : 0.2f * f;
      hsum[hk[k]] += lr * attv[k];
    }
    // wave-wide all-reduce per head
#pragma unroll
    for (int h = 0; h < NHEAD; ++h) {
#pragma unroll
      for (int off = 32; off > 0; off >>= 1)
        hsum[h] += __shfl_xor(hsum[h], off, 64);
    }
    // online softmax update
    float w[NHEAD], sc[NHEAD];
#pragma unroll
    for (int h = 0; h < NHEAD; ++h) {
      float s = hsum[h];
      float nm = fmaxf(m[h], s);
      sc[h] = __expf(m[h] - nm);
      w[h] = __expf(s - nm);
      den[h] = den[h] * sc[h] + w[h];
      m[h] = nm;
    }
#pragma unroll
    for (int k = 0; k < SLOTS; ++k)
      acc[k] = acc[k] * sc[hk[k]] + w[hk[k]] * xlv[k];
  }

#pragma unroll
  for (int k = 0; k < SLOTS; ++k) {
    int slot = lane + 64 * k;
    if (slot < HCDIM)
      out[(size_t)d * HCDIM + slot] = acc[k] / (den[hk[k]] + 1e-16f) + bvec[slot];
  }
}

// ======================= BatchNorm =======================
__global__ __launch_bounds__(320) void k_bn_reduce(const float* __restrict__ h,
                                                   float* __restrict__ colsum,
                                                   float* __restrict__ colsq,
                                                   int n, int rows_per_block) {
  int c = threadIdx.x;
  if (c >= HCDIM) return;
  int r0 = blockIdx.x * rows_per_block;
  int r1 = min(r0 + rows_per_block, n);
  float s = 0.f, s2 = 0.f;
  for (int r = r0; r < r1; ++r) {
    float v = h[(size_t)r * HCDIM + c];
    s += v;
    s2 += v * v;
  }
  atomicAdd(&colsum[c], s);
  atomicAdd(&colsq[c], s2);
}

__global__ void k_bn_apply(float* __restrict__ h, const float* __restrict__ colsum,
                           const float* __restrict__ colsq,
                           const float* __restrict__ gamma, const float* __restrict__ beta,
                           int total, float invN) {
  int i = blockIdx.x * blockDim.x + threadIdx.x;
  if (i >= total) return;
  int c = i % HCDIM;
  float mu = colsum[c] * invN;
  float var = colsq[c] * invN - mu * mu;
  float v = (h[i] - mu) * rsqrtf(var + BN_EPS) * gamma[c] + beta[c];
  h[i] = (v > 0.f) ? v : 0.01f * v;
}

// ======================= classifier: out[N,2] = h @ Wc^T + bc =======================
__global__ __launch_bounds__(256) void k_classifier(const float* __restrict__ h,
                                                    const float* __restrict__ Wc,
                                                    const float* __restrict__ bc,
                                                    float* __restrict__ out, int n) {
  int wave = threadIdx.x >> 6;
  int lane = threadIdx.x & 63;
  int r = blockIdx.x * 4 + wave;
  if (r >= n) return;
  float a0 = 0.f, a1 = 0.f;
#pragma unroll
  for (int k = 0; k < SLOTS; ++k) {
    int slot = lane + 64 * k;
    if (slot < HCDIM) {
      float v = h[(size_t)r * HCDIM + slot];
      a0 += v * Wc[slot];
      a1 += v * Wc[HCDIM + slot];
    }
  }
#pragma unroll
  for (int off = 32; off > 0; off >>= 1) {
    a0 += __shfl_xor(a0, off, 64);
    a1 += __shfl_xor(a1, off, 64);
  }
  if (lane == 0) {
    out[(size_t)2 * r] = a0 + bc[0];
    out[(size_t)2 * r + 1] = a1 + bc[1];
  }
}

// ======================= host launch =======================
extern "C" void kernel_launch(void* const* d_in, const int* in_sizes, int n_in,
                              void* d_out, int out_size, void* d_ws, size_t ws_size,
                              hipStream_t stream) {
  const float* x      = (const float*)d_in[0];
  const int*   eidx   = (const int*)d_in[1];
  const float* Wl1    = (const float*)d_in[2];
  const float* bl1    = (const float*)d_in[3];
  const float* Wr1    = (const float*)d_in[4];
  const float* br1    = (const float*)d_in[5];
  const float* att1   = (const float*)d_in[6];
  const float* b1     = (const float*)d_in[7];
  const float* Wl2    = (const float*)d_in[8];
  const float* bl2    = (const float*)d_in[9];
  const float* Wr2    = (const float*)d_in[10];
  const float* br2    = (const float*)d_in[11];
  const float* att2   = (const float*)d_in[12];
  const float* b2     = (const float*)d_in[13];
  const float* gamma  = (const float*)d_in[14];
  const float* beta   = (const float*)d_in[15];
  const float* Wc     = (const float*)d_in[16];
  const float* bc     = (const float*)d_in[17];
  float* out = (float*)d_out;

  const int FIN = 128;
  const int N = in_sizes[0] / FIN;   // 50000
  const int E = in_sizes[1] / 2;     // 800000
  const int NHC = N * HCDIM;

  const int* src = eidx;
  const int* dst = eidx + E;

  // workspace layout
  float* xl     = (float*)d_ws;
  float* xr     = xl + NHC;
  float* h      = xr + NHC;
  float* colsum = h + NHC;
  float* colsq  = colsum + HCDIM;
  int* ibase    = (int*)(colsq + HCDIM);
  int* deg      = ibase;
  int* row_ptr  = deg + N;          // N+1
  int* cursor   = row_ptr + N + 1;
  int* bsum     = cursor + N;       // 256
  int* boff     = bsum + 256;       // 256
  int* csr_src  = boff + 256;       // E

  const int G = (N + 255) / 256;        // 196 scan blocks
  const int EB = (E + 255) / 256;       // edge-parallel blocks
  const int AGGB = (N + 3) / 4;         // 4 waves per block

  // ---- CSR build (shared by both layers) ----
  k_zero_i32<<<G, 256, 0, stream>>>(deg, N);
  k_hist<<<EB, 256, 0, stream>>>(dst, deg, E);
  k_block_sum<<<G, 256, 0, stream>>>(deg, bsum, N);
  k_scan_small<<<1, 256, 0, stream>>>(bsum, boff, G);
  k_scan_final<<<G, 256, 0, stream>>>(deg, boff, row_ptr, N);
  k_fill_cursor<<<G, 256, 0, stream>>>(row_ptr, cursor, N, E);
  k_csr_fill<<<EB, 256, 0, stream>>>(src, dst, cursor, csr_src, E);

  dim3 gemm_grid((N + GBM - 1) / GBM, (HCDIM + GBN - 1) / GBN);

  // ---- layer 1 ----
  k_gemm_nt<<<gemm_grid, 256, 0, stream>>>(x, Wl1, bl1, xl, N, HCDIM, FIN);
  k_gemm_nt<<<gemm_grid, 256, 0, stream>>>(x, Wr1, br1, xr, N, HCDIM, FIN);
  k_agg<<<AGGB, 256, 0, stream>>>(xl, xr, csr_src, row_ptr, att1, b1, h, N);

  const int RPB = (N + 255) / 256;  // rows per bn-reduce block
  k_zero_f32<<<1, 2 * HCDIM, 0, stream>>>(colsum, 2 * HCDIM);
  k_bn_reduce<<<256, 320, 0, stream>>>(h, colsum, colsq, N, RPB);
  k_bn_apply<<<(NHC + 255) / 256, 256, 0, stream>>>(h, colsum, colsq, gamma, beta,
                                                    NHC, 1.f / (float)N);

  // ---- layer 2 ----
  k_gemm_nt<<<gemm_grid, 256, 0, stream>>>(h, Wl2, bl2, xl, N, HCDIM, HCDIM);
  k_gemm_nt<<<gemm_grid, 256, 0, stream>>>(h, Wr2, br2, xr, N, HCDIM, HCDIM);
  k_agg<<<AGGB, 256, 0, stream>>>(xl, xr, csr_src, row_ptr, att2, b2, h, N);

  k_zero_f32<<<1, 2 * HCDIM, 0, stream>>>(colsum, 2 * HCDIM);
  k_bn_reduce<<<256, 320, 0, stream>>>(h, colsum, colsq, N, RPB);
  k_bn_apply<<<(NHC + 255) / 256, 256, 0, stream>>>(h, colsum, colsq, gamma, beta,
                                                    NHC, 1.f / (float)N);

  // ---- classifier ----
  k_classifier<<<AGGB, 256, 0, stream>>>(h, Wc, bc, out, N);
}

// Round 2
// 1021.887 us; speedup vs baseline: 1.5208x; 1.5208x over previous
//
#include <hip/hip_runtime.h>

#define HCDIM 292
#define NHEAD 4
#define CDIM 73
#define SLOTS 5
#define BN_EPS 1e-5f

using u16x8 = __attribute__((ext_vector_type(8))) unsigned short;
using s16x8 = __attribute__((ext_vector_type(8))) short;   // 8 bf16 (4 VGPRs) MFMA frag
using f32x4 = __attribute__((ext_vector_type(4))) float;   // MFMA acc

__device__ inline ushort f2bf(float f) {       // RTN-even fp32 -> bf16
  unsigned int u = __float_as_uint(f);
  u += 0x7FFFu + ((u >> 16) & 1u);
  return (ushort)(u >> 16);
}
__device__ inline float bf2f(ushort v) {
  return __uint_as_float(((unsigned int)v) << 16);
}

// ======================= utility =======================
__global__ void k_zero_i32(int* __restrict__ p, int n) {
  int i = blockIdx.x * blockDim.x + threadIdx.x;
  if (i < n) p[i] = 0;
}
__global__ void k_zero_f32(float* __restrict__ p, int n) {
  int i = blockIdx.x * blockDim.x + threadIdx.x;
  if (i < n) p[i] = 0.f;
}

// fp32 [rows,Kin] -> bf16 [rows,Kpad] with zero pad (re-written every call; ws is poisoned)
__global__ void k_cvt_pad(const float* __restrict__ src, ushort* __restrict__ dst,
                          int rows, int Kin, int Kpad) {
  int i = blockIdx.x * blockDim.x + threadIdx.x;
  if (i >= rows * Kpad) return;
  int r = i / Kpad;
  int k = i - r * Kpad;
  dst[i] = (k < Kin) ? f2bf(src[(size_t)r * Kin + k]) : (ushort)0;
}

// ======================= CSR build =======================
__global__ void k_hist(const int* __restrict__ dst, int* __restrict__ deg, int E) {
  int i = blockIdx.x * blockDim.x + threadIdx.x;
  if (i < E) atomicAdd(&deg[dst[i]], 1);
}

__global__ __launch_bounds__(256) void k_block_sum(const int* __restrict__ deg,
                                                   int* __restrict__ bsum, int n) {
  __shared__ int s[256];
  int i = blockIdx.x * 256 + threadIdx.x;
  s[threadIdx.x] = (i < n) ? deg[i] : 0;
  __syncthreads();
  for (int off = 128; off > 0; off >>= 1) {
    if (threadIdx.x < off) s[threadIdx.x] += s[threadIdx.x + off];
    __syncthreads();
  }
  if (threadIdx.x == 0) bsum[blockIdx.x] = s[0];
}

__global__ __launch_bounds__(256) void k_scan_small(const int* __restrict__ bsum,
                                                    int* __restrict__ boff, int G) {
  __shared__ int s[256];
  int t = threadIdx.x;
  int v = (t < G) ? bsum[t] : 0;
  s[t] = v;
  __syncthreads();
  for (int off = 1; off < 256; off <<= 1) {
    int tv = (t >= off) ? s[t - off] : 0;
    __syncthreads();
    s[t] += tv;
    __syncthreads();
  }
  if (t < G) boff[t] = s[t] - v;
}

__global__ __launch_bounds__(256) void k_scan_final(const int* __restrict__ deg,
                                                    const int* __restrict__ boff,
                                                    int* __restrict__ row_ptr, int n) {
  __shared__ int s[256];
  int t = threadIdx.x;
  int i = blockIdx.x * 256 + t;
  int v = (i < n) ? deg[i] : 0;
  s[t] = v;
  __syncthreads();
  for (int off = 1; off < 256; off <<= 1) {
    int tv = (t >= off) ? s[t - off] : 0;
    __syncthreads();
    s[t] += tv;
    __syncthreads();
  }
  if (i < n) row_ptr[i] = boff[blockIdx.x] + s[t] - v;
}

__global__ void k_fill_cursor(int* __restrict__ row_ptr, int* __restrict__ cursor,
                              int n, int E) {
  int i = blockIdx.x * blockDim.x + threadIdx.x;
  if (i < n) cursor[i] = row_ptr[i];
  if (i == 0) row_ptr[n] = E;
}

__global__ void k_csr_fill(const int* __restrict__ srcs, const int* __restrict__ dsts,
                           int* __restrict__ cursor, int* __restrict__ csr_src, int E) {
  int i = blockIdx.x * blockDim.x + threadIdx.x;
  if (i < E) {
    int pos = atomicAdd(&cursor[dsts[i]], 1);
    csr_src[pos] = srcs[i];
  }
}

// ======================= bf16 MFMA GEMM =======================
// out{0,1}[M,Nc](bf16) = bf16(A[M,Ks] @ W{0,1}[Nc,Ks]^T + bias{0,1})
// 128x128 tile, BK=32, 256 thr = 4 waves (2x2 of 64x64), 4x4 x mfma_16x16x32_bf16.
// LDS rows padded to 40 ushorts (80 B = 20 banks) -> <=2-way aliasing (free).
#define LDSK 40

__global__ __launch_bounds__(256) void k_gemm_mfma(
    const ushort* __restrict__ A, const ushort* __restrict__ W0,
    const ushort* __restrict__ W1, const float* __restrict__ b0,
    const float* __restrict__ b1, ushort* __restrict__ out0,
    ushort* __restrict__ out1, int M, int Nc, int Ks) {
  __shared__ ushort As[128 * LDSK];
  __shared__ ushort Bs[128 * LDSK];
  const ushort* W = blockIdx.z ? W1 : W0;
  const float* bias = blockIdx.z ? b1 : b0;
  ushort* out = blockIdx.z ? out1 : out0;
  const int bm = blockIdx.x * 128;
  const int bn = blockIdx.y * 128;
  const int tid = threadIdx.x;
  const int wave = tid >> 6, lane = tid & 63;
  const int quad = lane >> 4, lr = lane & 15;
  const int wm = (wave & 1) * 64, wn = (wave >> 1) * 64;

  f32x4 acc[4][4] = {};

  for (int k0 = 0; k0 < Ks; k0 += 32) {
#pragma unroll
    for (int part = 0; part < 2; ++part) {
      int e = tid + part * 256;          // [0,512)
      int row = e >> 2;                  // [0,128)
      int kg = (e & 3) * 8;
      int gm = bm + row;
      u16x8 av = {};
      if (gm < M) av = *(const u16x8*)(A + (size_t)gm * Ks + k0 + kg);
      *(u16x8*)(As + row * LDSK + kg) = av;
      int gn = bn + row;
      u16x8 bv = {};
      if (gn < Nc) bv = *(const u16x8*)(W + (size_t)gn * Ks + k0 + kg);
      *(u16x8*)(Bs + row * LDSK + kg) = bv;
    }
    __syncthreads();
    s16x8 af[4], bf[4];
#pragma unroll
    for (int i = 0; i < 4; ++i) {
      af[i] = *(const s16x8*)(As + (wm + i * 16 + lr) * LDSK + quad * 8);
      bf[i] = *(const s16x8*)(Bs + (wn + i * 16 + lr) * LDSK + quad * 8);
    }
#pragma unroll
    for (int mi = 0; mi < 4; ++mi)
#pragma unroll
      for (int ni = 0; ni < 4; ++ni)
        acc[mi][ni] = __builtin_amdgcn_mfma_f32_16x16x32_bf16(af[mi], bf[ni],
                                                              acc[mi][ni], 0, 0, 0);
    __syncthreads();
  }

  // C/D layout: n = lane&15, m = quad*4 + reg   [measured m89/m91]
#pragma unroll
  for (int mi = 0; mi < 4; ++mi) {
#pragma unroll
    for (int r = 0; r < 4; ++r) {
      int gm = bm + wm + mi * 16 + quad * 4 + r;
      if (gm >= M) continue;
#pragma unroll
      for (int ni = 0; ni < 4; ++ni) {
        int gn = bn + wn + ni * 16 + lr;
        if (gn < Nc)
          out[(size_t)gm * Nc + gn] = f2bf(acc[mi][ni][r] + bias[gn]);
      }
    }
  }
}

// ======================= fused GATv2 attention (bf16 xl/xr) =======================
__global__ __launch_bounds__(256) void k_agg(const ushort* __restrict__ xl,
                                             const ushort* __restrict__ xr,
                                             const int* __restrict__ csr_src,
                                             const int* __restrict__ row_ptr,
                                             const float* __restrict__ att,
                                             const float* __restrict__ bvec,
                                             float* __restrict__ out, int n) {
  int wave = threadIdx.x >> 6;
  int lane = threadIdx.x & 63;
  int d = blockIdx.x * 4 + wave;
  if (d >= n) return;
  int start = row_ptr[d];
  int end = row_ptr[d + 1];

  float xrv[SLOTS], attv[SLOTS], acc[SLOTS];
  int hk[SLOTS];
#pragma unroll
  for (int k = 0; k < SLOTS; ++k) {
    int slot = lane + 64 * k;
    bool act = slot < HCDIM;
    xrv[k] = act ? bf2f(xr[(size_t)d * HCDIM + slot]) : 0.f;
    attv[k] = act ? att[slot] : 0.f;
    hk[k] = act ? (slot / CDIM) : 0;
    acc[k] = 0.f;
  }
  float m[NHEAD] = {-1e30f, -1e30f, -1e30f, -1e30f};
  float den[NHEAD] = {0.f, 0.f, 0.f, 0.f};

  for (int e = start; e < end; ++e) {
    int src = csr_src[e];
    float xlv[SLOTS];
    float hsum[NHEAD] = {0.f, 0.f, 0.f, 0.f};
#pragma unroll
    for (int k = 0; k < SLOTS; ++k) {
      int slot = lane + 64 * k;
      float v = (slot < HCDIM) ? bf2f(xl[(size_t)src * HCDIM + slot]) : 0.f;
      xlv[k] = v;
      float f = v + xrv[k];
      float lrf = (f > 0.f) ? f : 0.2f * f;
      hsum[hk[k]] += lrf * attv[k];
    }
#pragma unroll
    for (int h = 0; h < NHEAD; ++h) {
#pragma unroll
      for (int off = 32; off > 0; off >>= 1)
        hsum[h] += __shfl_xor(hsum[h], off, 64);
    }
    float w[NHEAD], sc[NHEAD];
#pragma unroll
    for (int h = 0; h < NHEAD; ++h) {
      float s = hsum[h];
      float nm = fmaxf(m[h], s);
      sc[h] = __expf(m[h] - nm);
      w[h] = __expf(s - nm);
      den[h] = den[h] * sc[h] + w[h];
      m[h] = nm;
    }
#pragma unroll
    for (int k = 0; k < SLOTS; ++k)
      acc[k] = acc[k] * sc[hk[k]] + w[hk[k]] * xlv[k];
  }

#pragma unroll
  for (int k = 0; k < SLOTS; ++k) {
    int slot = lane + 64 * k;
    if (slot < HCDIM)
      out[(size_t)d * HCDIM + slot] = acc[k] / (den[hk[k]] + 1e-16f) + bvec[slot];
  }
}

// ======================= BatchNorm =======================
__global__ __launch_bounds__(320) void k_bn_reduce(const float* __restrict__ h,
                                                   float* __restrict__ colsum,
                                                   float* __restrict__ colsq,
                                                   int n, int rows_per_block) {
  int c = threadIdx.x;
  if (c >= HCDIM) return;
  int r0 = blockIdx.x * rows_per_block;
  int r1 = min(r0 + rows_per_block, n);
  float s = 0.f, s2 = 0.f;
  for (int r = r0; r < r1; ++r) {
    float v = h[(size_t)r * HCDIM + c];
    s += v;
    s2 += v * v;
  }
  atomicAdd(&colsum[c], s);
  atomicAdd(&colsq[c], s2);
}

__global__ void k_bn_apply(float* __restrict__ h, const float* __restrict__ colsum,
                           const float* __restrict__ colsq,
                           const float* __restrict__ gamma, const float* __restrict__ beta,
                           int total, float invN) {
  int i = blockIdx.x * blockDim.x + threadIdx.x;
  if (i >= total) return;
  int c = i % HCDIM;
  float mu = colsum[c] * invN;
  float var = colsq[c] * invN - mu * mu;
  float v = (h[i] - mu) * rsqrtf(var + BN_EPS) * gamma[c] + beta[c];
  h[i] = (v > 0.f) ? v : 0.01f * v;
}

// ======================= classifier =======================
__global__ __launch_bounds__(256) void k_classifier(const float* __restrict__ h,
                                                    const float* __restrict__ Wc,
                                                    const float* __restrict__ bc,
                                                    float* __restrict__ out, int n) {
  int wave = threadIdx.x >> 6;
  int lane = threadIdx.x & 63;
  int r = blockIdx.x * 4 + wave;
  if (r >= n) return;
  float a0 = 0.f, a1 = 0.f;
#pragma unroll
  for (int k = 0; k < SLOTS; ++k) {
    int slot = lane + 64 * k;
    if (slot < HCDIM) {
      float v = h[(size_t)r * HCDIM + slot];
      a0 += v * Wc[slot];
      a1 += v * Wc[HCDIM + slot];
    }
  }
#pragma unroll
  for (int off = 32; off > 0; off >>= 1) {
    a0 += __shfl_xor(a0, off, 64);
    a1 += __shfl_xor(a1, off, 64);
  }
  if (lane == 0) {
    out[(size_t)2 * r] = a0 + bc[0];
    out[(size_t)2 * r + 1] = a1 + bc[1];
  }
}

// ======================= host launch =======================
extern "C" void kernel_launch(void* const* d_in, const int* in_sizes, int n_in,
                              void* d_out, int out_size, void* d_ws, size_t ws_size,
                              hipStream_t stream) {
  const float* x      = (const float*)d_in[0];
  const int*   eidx   = (const int*)d_in[1];
  const float* Wl1    = (const float*)d_in[2];
  const float* bl1    = (const float*)d_in[3];
  const float* Wr1    = (const float*)d_in[4];
  const float* br1    = (const float*)d_in[5];
  const float* att1   = (const float*)d_in[6];
  const float* b1     = (const float*)d_in[7];
  const float* Wl2    = (const float*)d_in[8];
  const float* bl2    = (const float*)d_in[9];
  const float* Wr2    = (const float*)d_in[10];
  const float* br2    = (const float*)d_in[11];
  const float* att2   = (const float*)d_in[12];
  const float* b2     = (const float*)d_in[13];
  const float* gamma  = (const float*)d_in[14];
  const float* beta   = (const float*)d_in[15];
  const float* Wc     = (const float*)d_in[16];
  const float* bc     = (const float*)d_in[17];
  float* out = (float*)d_out;

  const int FIN = 128;
  const int KP2 = 320;               // HCDIM padded to mult of 32
  const int N = in_sizes[0] / FIN;   // 50000
  const int E = in_sizes[1] / 2;     // 800000
  const int NHC = N * HCDIM;

  const int* src = eidx;
  const int* dst = eidx + E;

  // ---- workspace layout (all 16B-aligned offsets) ----
  float* h       = (float*)d_ws;            // N*HCDIM f32
  ushort* xl_b   = (ushort*)(h + NHC);      // N*HCDIM bf16
  ushort* xr_b   = xl_b + NHC;              // N*HCDIM bf16
  ushort* abuf   = xr_b + NHC;              // N*KP2 bf16 (xb layer1 / hb layer2)
  ushort* wl_b   = abuf + (size_t)N * KP2;  // HCDIM*KP2 bf16
  ushort* wr_b   = wl_b + HCDIM * KP2;
  float* colsum  = (float*)(wr_b + HCDIM * KP2);
  float* colsq   = colsum + HCDIM;
  int* deg       = (int*)(colsq + HCDIM);
  int* row_ptr   = deg + N;                 // N+1
  int* cursor    = row_ptr + N + 1;
  int* bsum      = cursor + N;              // 256
  int* boff      = bsum + 256;              // 256
  int* csr_src   = boff + 256;              // E

  const int G = (N + 255) / 256;
  const int EB = (E + 255) / 256;
  const int AGGB = (N + 3) / 4;

  // ---- CSR build ----
  k_zero_i32<<<G, 256, 0, stream>>>(deg, N);
  k_hist<<<EB, 256, 0, stream>>>(dst, deg, E);
  k_block_sum<<<G, 256, 0, stream>>>(deg, bsum, N);
  k_scan_small<<<1, 256, 0, stream>>>(bsum, boff, G);
  k_scan_final<<<G, 256, 0, stream>>>(deg, boff, row_ptr, N);
  k_fill_cursor<<<G, 256, 0, stream>>>(row_ptr, cursor, N, E);
  k_csr_fill<<<EB, 256, 0, stream>>>(src, dst, cursor, csr_src, E);

  dim3 gemm_grid((N + 127) / 128, (HCDIM + 127) / 128, 2);

  // ---- layer 1 ----
  k_cvt_pad<<<(N * FIN + 255) / 256, 256, 0, stream>>>(x, abuf, N, FIN, FIN);
  k_cvt_pad<<<(HCDIM * FIN + 255) / 256, 256, 0, stream>>>(Wl1, wl_b, HCDIM, FIN, FIN);
  k_cvt_pad<<<(HCDIM * FIN + 255) / 256, 256, 0, stream>>>(Wr1, wr_b, HCDIM, FIN, FIN);
  k_gemm_mfma<<<gemm_grid, 256, 0, stream>>>(abuf, wl_b, wr_b, bl1, br1,
                                             xl_b, xr_b, N, HCDIM, FIN);
  k_agg<<<AGGB, 256, 0, stream>>>(xl_b, xr_b, csr_src, row_ptr, att1, b1, h, N);

  const int RPB = (N + 255) / 256;
  k_zero_f32<<<1, 2 * HCDIM, 0, stream>>>(colsum, 2 * HCDIM);
  k_bn_reduce<<<256, 320, 0, stream>>>(h, colsum, colsq, N, RPB);
  k_bn_apply<<<(NHC + 255) / 256, 256, 0, stream>>>(h, colsum, colsq, gamma, beta,
                                                    NHC, 1.f / (float)N);

  // ---- layer 2 ----
  k_cvt_pad<<<(N * KP2 + 255) / 256, 256, 0, stream>>>(h, abuf, N, HCDIM, KP2);
  k_cvt_pad<<<(HCDIM * KP2 + 255) / 256, 256, 0, stream>>>(Wl2, wl_b, HCDIM, HCDIM, KP2);
  k_cvt_pad<<<(HCDIM * KP2 + 255) / 256, 256, 0, stream>>>(Wr2, wr_b, HCDIM, HCDIM, KP2);
  k_gemm_mfma<<<gemm_grid, 256, 0, stream>>>(abuf, wl_b, wr_b, bl2, br2,
                                             xl_b, xr_b, N, HCDIM, KP2);
  k_agg<<<AGGB, 256, 0, stream>>>(xl_b, xr_b, csr_src, row_ptr, att2, b2, h, N);

  k_zero_f32<<<1, 2 * HCDIM, 0, stream>>>(colsum, 2 * HCDIM);
  k_bn_reduce<<<256, 320, 0, stream>>>(h, colsum, colsq, N, RPB);
  k_bn_apply<<<(NHC + 255) / 256, 256, 0, stream>>>(h, colsum, colsq, gamma, beta,
                                                    NHC, 1.f / (float)N);

  // ---- classifier ----
  k_classifier<<<AGGB, 256, 0, stream>>>(h, Wc, bc, out, N);
}

// Round 3
// 819.184 us; speedup vs baseline: 1.8972x; 1.2474x over previous
//
#include <hip/hip_runtime.h>

#define HCDIM 292
#define NHEAD 4
#define CDIM 73
#define SLOTS 5
#define KP2 320
#define BN_EPS 1e-5f

using u16x8 = __attribute__((ext_vector_type(8))) unsigned short;
using s16x8 = __attribute__((ext_vector_type(8))) short;   // 8 bf16 (4 VGPRs) MFMA frag
using f32x4 = __attribute__((ext_vector_type(4))) float;   // MFMA acc

__device__ inline ushort f2bf(float f) {       // RTN-even fp32 -> bf16
  unsigned int u = __float_as_uint(f);
  u += 0x7FFFu + ((u >> 16) & 1u);
  return (ushort)(u >> 16);
}
__device__ inline float bf2f(ushort v) {
  return __uint_as_float(((unsigned int)v) << 16);
}

// ======================= utility =======================
__global__ void k_zero_i32(int* __restrict__ p, int n) {
  int i = blockIdx.x * blockDim.x + threadIdx.x;
  if (i < n) p[i] = 0;
}
__global__ void k_zero_f32(float* __restrict__ p, int n) {
  int i = blockIdx.x * blockDim.x + threadIdx.x;
  if (i < n) p[i] = 0.f;
}

// fp32 [rows,Kin] -> bf16 [rows,Kpad] zero-padded
__global__ void k_cvt_pad(const float* __restrict__ src, ushort* __restrict__ dst,
                          int rows, int Kin, int Kpad) {
  int i = blockIdx.x * blockDim.x + threadIdx.x;
  if (i >= rows * Kpad) return;
  int r = i / Kpad;
  int k = i - r * Kpad;
  dst[i] = (k < Kin) ? f2bf(src[(size_t)r * Kin + k]) : (ushort)0;
}

// ======================= CSR build =======================
__global__ void k_hist(const int* __restrict__ dst, int* __restrict__ deg, int E) {
  int i = blockIdx.x * blockDim.x + threadIdx.x;
  if (i < E) atomicAdd(&deg[dst[i]], 1);
}

__global__ __launch_bounds__(256) void k_block_sum(const int* __restrict__ deg,
                                                   int* __restrict__ bsum, int n) {
  __shared__ int s[256];
  int i = blockIdx.x * 256 + threadIdx.x;
  s[threadIdx.x] = (i < n) ? deg[i] : 0;
  __syncthreads();
  for (int off = 128; off > 0; off >>= 1) {
    if (threadIdx.x < off) s[threadIdx.x] += s[threadIdx.x + off];
    __syncthreads();
  }
  if (threadIdx.x == 0) bsum[blockIdx.x] = s[0];
}

__global__ __launch_bounds__(256) void k_scan_small(const int* __restrict__ bsum,
                                                    int* __restrict__ boff, int G) {
  __shared__ int s[256];
  int t = threadIdx.x;
  int v = (t < G) ? bsum[t] : 0;
  s[t] = v;
  __syncthreads();
  for (int off = 1; off < 256; off <<= 1) {
    int tv = (t >= off) ? s[t - off] : 0;
    __syncthreads();
    s[t] += tv;
    __syncthreads();
  }
  if (t < G) boff[t] = s[t] - v;
}

__global__ __launch_bounds__(256) void k_scan_final(const int* __restrict__ deg,
                                                    const int* __restrict__ boff,
                                                    int* __restrict__ row_ptr, int n) {
  __shared__ int s[256];
  int t = threadIdx.x;
  int i = blockIdx.x * 256 + t;
  int v = (i < n) ? deg[i] : 0;
  s[t] = v;
  __syncthreads();
  for (int off = 1; off < 256; off <<= 1) {
    int tv = (t >= off) ? s[t - off] : 0;
    __syncthreads();
    s[t] += tv;
    __syncthreads();
  }
  if (i < n) row_ptr[i] = boff[blockIdx.x] + s[t] - v;
}

__global__ void k_fill_cursor(int* __restrict__ row_ptr, int* __restrict__ cursor,
                              int n, int E) {
  int i = blockIdx.x * blockDim.x + threadIdx.x;
  if (i < n) cursor[i] = row_ptr[i];
  if (i == 0) row_ptr[n] = E;
}

__global__ void k_csr_fill(const int* __restrict__ srcs, const int* __restrict__ dsts,
                           int* __restrict__ cursor, int* __restrict__ csr_src, int E) {
  int i = blockIdx.x * blockDim.x + threadIdx.x;
  if (i < E) {
    int pos = atomicAdd(&cursor[dsts[i]], 1);
    csr_src[pos] = srcs[i];
  }
}

// ======================= bf16 MFMA GEMM (unchanged from R2) =======================
#define LDSK 40

__global__ __launch_bounds__(256) void k_gemm_mfma(
    const ushort* __restrict__ A, const ushort* __restrict__ W0,
    const ushort* __restrict__ W1, const float* __restrict__ b0,
    const float* __restrict__ b1, ushort* __restrict__ out0,
    ushort* __restrict__ out1, int M, int Nc, int Ks) {
  __shared__ ushort As[128 * LDSK];
  __shared__ ushort Bs[128 * LDSK];
  const ushort* W = blockIdx.z ? W1 : W0;
  const float* bias = blockIdx.z ? b1 : b0;
  ushort* out = blockIdx.z ? out1 : out0;
  const int bm = blockIdx.x * 128;
  const int bn = blockIdx.y * 128;
  const int tid = threadIdx.x;
  const int wave = tid >> 6, lane = tid & 63;
  const int quad = lane >> 4, lr = lane & 15;
  const int wm = (wave & 1) * 64, wn = (wave >> 1) * 64;

  f32x4 acc[4][4] = {};

  for (int k0 = 0; k0 < Ks; k0 += 32) {
#pragma unroll
    for (int part = 0; part < 2; ++part) {
      int e = tid + part * 256;
      int row = e >> 2;
      int kg = (e & 3) * 8;
      int gm = bm + row;
      u16x8 av = {};
      if (gm < M) av = *(const u16x8*)(A + (size_t)gm * Ks + k0 + kg);
      *(u16x8*)(As + row * LDSK + kg) = av;
      int gn = bn + row;
      u16x8 bv = {};
      if (gn < Nc) bv = *(const u16x8*)(W + (size_t)gn * Ks + k0 + kg);
      *(u16x8*)(Bs + row * LDSK + kg) = bv;
    }
    __syncthreads();
    s16x8 af[4], bf[4];
#pragma unroll
    for (int i = 0; i < 4; ++i) {
      af[i] = *(const s16x8*)(As + (wm + i * 16 + lr) * LDSK + quad * 8);
      bf[i] = *(const s16x8*)(Bs + (wn + i * 16 + lr) * LDSK + quad * 8);
    }
#pragma unroll
    for (int mi = 0; mi < 4; ++mi)
#pragma unroll
      for (int ni = 0; ni < 4; ++ni)
        acc[mi][ni] = __builtin_amdgcn_mfma_f32_16x16x32_bf16(af[mi], bf[ni],
                                                              acc[mi][ni], 0, 0, 0);
    __syncthreads();
  }

#pragma unroll
  for (int mi = 0; mi < 4; ++mi) {
#pragma unroll
    for (int r = 0; r < 4; ++r) {
      int gm = bm + wm + mi * 16 + quad * 4 + r;
      if (gm >= M) continue;
#pragma unroll
      for (int ni = 0; ni < 4; ++ni) {
        int gn = bn + wn + ni * 16 + lr;
        if (gn < Nc)
          out[(size_t)gm * Nc + gn] = f2bf(acc[mi][ni][r] + bias[gn]);
      }
    }
  }
}

// ======================= per-node attention pre-dots =======================
// pl[n,h] = 0.6 * sum_c xl[n,h,c]*att[h,c] ; pr likewise from xr.
__global__ __launch_bounds__(256) void k_pre(const ushort* __restrict__ xl,
                                             const ushort* __restrict__ xr,
                                             const float* __restrict__ att,
                                             float* __restrict__ pl,
                                             float* __restrict__ pr, int n) {
  int wave = threadIdx.x >> 6, lane = threadIdx.x & 63;
  int d = blockIdx.x * 4 + wave;
  if (d >= n) return;
  int hgrp = lane >> 4, li = lane & 15;
  float Ta = 0.f, Tb = 0.f;
#pragma unroll
  for (int k = 0; k < SLOTS; ++k) {
    int c = li + 16 * k;
    bool act = c < CDIM;
    int f = hgrp * CDIM + (act ? c : 0);
    float a = act ? att[f] : 0.f;
    Ta += bf2f(xl[(size_t)d * HCDIM + f]) * a;
    Tb += bf2f(xr[(size_t)d * HCDIM + f]) * a;
  }
#pragma unroll
  for (int off = 1; off < 16; off <<= 1) {
    Ta += __shfl_xor(Ta, off, 64);
    Tb += __shfl_xor(Tb, off, 64);
  }
  if (li == 0) {
    pl[d * 4 + hgrp] = 0.6f * Ta;
    pr[d * 4 + hgrp] = 0.6f * Tb;
  }
}

// ======================= fused GATv2 attention (head-grouped lanes) =======================
// lrelu_{0.2}(x) = 0.6x + 0.4|x|  =>  s = (pl+pr) + sum |xl+xr| * (0.4*att)
// direct exp (softmax shift-invariant; |s| = O(1), clamp at 60).
__global__ __launch_bounds__(256) void k_agg(const ushort* __restrict__ xl,
                                             const ushort* __restrict__ xr,
                                             const float* __restrict__ pl,
                                             const float* __restrict__ pr,
                                             const int* __restrict__ csr_src,
                                             const int* __restrict__ row_ptr,
                                             const float* __restrict__ att,
                                             const float* __restrict__ bvec,
                                             float* __restrict__ out, int n) {
  int wave = threadIdx.x >> 6, lane = threadIdx.x & 63;
  int d = blockIdx.x * 4 + wave;
  if (d >= n) return;
  int hgrp = lane >> 4, li = lane & 15;
  int start = row_ptr[d], end = row_ptr[d + 1];

  int fi[SLOTS];
  float xrv[SLOTS], attv[SLOTS], acc[SLOTS];
  bool act[SLOTS];
#pragma unroll
  for (int k = 0; k < SLOTS; ++k) {
    int c = li + 16 * k;
    act[k] = c < CDIM;
    fi[k] = hgrp * CDIM + (act[k] ? c : 0);      // clamped: loads stay in-bounds
    xrv[k] = bf2f(xr[(size_t)d * HCDIM + fi[k]]);
    attv[k] = act[k] ? 0.4f * att[fi[k]] : 0.f;  // inactive lanes contribute 0
    acc[k] = 0.f;
  }
  float prv = pr[d * 4 + hgrp];
  float den = 0.f;

  for (int e = start; e < end; ++e) {
    int s32 = csr_src[e];
    float plv = pl[s32 * 4 + hgrp];
    const ushort* row = xl + (size_t)s32 * HCDIM;
    float xlv[SLOTS], T = 0.f;
#pragma unroll
    for (int k = 0; k < SLOTS; ++k) {
      float v = bf2f(row[fi[k]]);
      xlv[k] = v;
      T = fmaf(fabsf(v + xrv[k]), attv[k], T);   // abs is a free VOP3 modifier
    }
    T += __shfl_xor(T, 1, 64);
    T += __shfl_xor(T, 2, 64);
    T += __shfl_xor(T, 4, 64);
    T += __shfl_xor(T, 8, 64);
    float s = fminf(T + plv + prv, 60.f);
    float w = __expf(s);
    den += w;
#pragma unroll
    for (int k = 0; k < SLOTS; ++k) acc[k] = fmaf(w, xlv[k], acc[k]);
  }

  float inv = 1.f / (den + 1e-16f);
#pragma unroll
  for (int k = 0; k < SLOTS; ++k)
    if (act[k])
      out[(size_t)d * HCDIM + fi[k]] = acc[k] * inv + bvec[fi[k]];
}

// ======================= BatchNorm =======================
__global__ __launch_bounds__(320) void k_bn_reduce(const float* __restrict__ h,
                                                   float* __restrict__ colsum,
                                                   float* __restrict__ colsq,
                                                   int n, int rows_per_block) {
  int c = threadIdx.x;
  if (c >= HCDIM) return;
  int r0 = blockIdx.x * rows_per_block;
  int r1 = min(r0 + rows_per_block, n);
  float s = 0.f, s2 = 0.f;
  for (int r = r0; r < r1; ++r) {
    float v = h[(size_t)r * HCDIM + c];
    s += v;
    s2 += v * v;
  }
  atomicAdd(&colsum[c], s);
  atomicAdd(&colsq[c], s2);
}

// BN + leaky-relu, write bf16 zero-padded [n,KP2] (feeds layer-2 GEMM directly)
__global__ __launch_bounds__(320) void k_bn_apply_bf(
    const float* __restrict__ h, const float* __restrict__ colsum,
    const float* __restrict__ colsq, const float* __restrict__ gamma,
    const float* __restrict__ beta, ushort* __restrict__ outb, int n, float invN) {
  int r = blockIdx.x, c = threadIdx.x;
  if (r >= n) return;
  ushort o = 0;
  if (c < HCDIM) {
    float mu = colsum[c] * invN;
    float var = colsq[c] * invN - mu * mu;
    float v = (h[(size_t)r * HCDIM + c] - mu) * rsqrtf(var + BN_EPS) * gamma[c] + beta[c];
    v = (v > 0.f) ? v : 0.01f * v;
    o = f2bf(v);
  }
  outb[(size_t)r * KP2 + c] = o;
}

// BN + leaky-relu, fp32 in place (feeds classifier)
__global__ __launch_bounds__(320) void k_bn_apply_f32(
    float* __restrict__ h, const float* __restrict__ colsum,
    const float* __restrict__ colsq, const float* __restrict__ gamma,
    const float* __restrict__ beta, int n, float invN) {
  int r = blockIdx.x, c = threadIdx.x;
  if (r >= n || c >= HCDIM) return;
  float mu = colsum[c] * invN;
  float var = colsq[c] * invN - mu * mu;
  float v = (h[(size_t)r * HCDIM + c] - mu) * rsqrtf(var + BN_EPS) * gamma[c] + beta[c];
  h[(size_t)r * HCDIM + c] = (v > 0.f) ? v : 0.01f * v;
}

// ======================= classifier =======================
__global__ __launch_bounds__(256) void k_classifier(const float* __restrict__ h,
                                                    const float* __restrict__ Wc,
                                                    const float* __restrict__ bc,
                                                    float* __restrict__ out, int n) {
  int wave = threadIdx.x >> 6;
  int lane = threadIdx.x & 63;
  int r = blockIdx.x * 4 + wave;
  if (r >= n) return;
  float a0 = 0.f, a1 = 0.f;
#pragma unroll
  for (int k = 0; k < SLOTS; ++k) {
    int slot = lane + 64 * k;
    if (slot < HCDIM) {
      float v = h[(size_t)r * HCDIM + slot];
      a0 += v * Wc[slot];
      a1 += v * Wc[HCDIM + slot];
    }
  }
#pragma unroll
  for (int off = 32; off > 0; off >>= 1) {
    a0 += __shfl_xor(a0, off, 64);
    a1 += __shfl_xor(a1, off, 64);
  }
  if (lane == 0) {
    out[(size_t)2 * r] = a0 + bc[0];
    out[(size_t)2 * r + 1] = a1 + bc[1];
  }
}

// ======================= host launch =======================
extern "C" void kernel_launch(void* const* d_in, const int* in_sizes, int n_in,
                              void* d_out, int out_size, void* d_ws, size_t ws_size,
                              hipStream_t stream) {
  const float* x      = (const float*)d_in[0];
  const int*   eidx   = (const int*)d_in[1];
  const float* Wl1    = (const float*)d_in[2];
  const float* bl1    = (const float*)d_in[3];
  const float* Wr1    = (const float*)d_in[4];
  const float* br1    = (const float*)d_in[5];
  const float* att1   = (const float*)d_in[6];
  const float* b1     = (const float*)d_in[7];
  const float* Wl2    = (const float*)d_in[8];
  const float* bl2    = (const float*)d_in[9];
  const float* Wr2    = (const float*)d_in[10];
  const float* br2    = (const float*)d_in[11];
  const float* att2   = (const float*)d_in[12];
  const float* b2     = (const float*)d_in[13];
  const float* gamma  = (const float*)d_in[14];
  const float* beta   = (const float*)d_in[15];
  const float* Wc     = (const float*)d_in[16];
  const float* bc     = (const float*)d_in[17];
  float* out = (float*)d_out;

  const int FIN = 128;
  const int N = in_sizes[0] / FIN;   // 50000
  const int E = in_sizes[1] / 2;     // 800000
  const int NHC = N * HCDIM;

  const int* src = eidx;
  const int* dst = eidx + E;

  // ---- workspace layout ----
  float* h       = (float*)d_ws;            // N*HCDIM f32
  ushort* xl_b   = (ushort*)(h + NHC);      // N*HCDIM bf16
  ushort* xr_b   = xl_b + NHC;              // N*HCDIM bf16
  ushort* abuf   = xr_b + NHC;              // N*KP2 bf16
  ushort* wl_b   = abuf + (size_t)N * KP2;  // HCDIM*KP2 bf16
  ushort* wr_b   = wl_b + HCDIM * KP2;
  float* pl      = (float*)(wr_b + HCDIM * KP2);  // N*4
  float* pr      = pl + (size_t)N * NHEAD;        // N*4
  float* colsum  = pr + (size_t)N * NHEAD;
  float* colsq   = colsum + HCDIM;
  int* deg       = (int*)(colsq + HCDIM);
  int* row_ptr   = deg + N;                 // N+1
  int* cursor    = row_ptr + N + 1;
  int* bsum      = cursor + N;              // 256
  int* boff      = bsum + 256;              // 256
  int* csr_src   = boff + 256;              // E

  const int G = (N + 255) / 256;
  const int EB = (E + 255) / 256;
  const int AGGB = (N + 3) / 4;

  // ---- CSR build ----
  k_zero_i32<<<G, 256, 0, stream>>>(deg, N);
  k_hist<<<EB, 256, 0, stream>>>(dst, deg, E);
  k_block_sum<<<G, 256, 0, stream>>>(deg, bsum, N);
  k_scan_small<<<1, 256, 0, stream>>>(bsum, boff, G);
  k_scan_final<<<G, 256, 0, stream>>>(deg, boff, row_ptr, N);
  k_fill_cursor<<<G, 256, 0, stream>>>(row_ptr, cursor, N, E);
  k_csr_fill<<<EB, 256, 0, stream>>>(src, dst, cursor, csr_src, E);

  dim3 gemm_grid((N + 127) / 128, (HCDIM + 127) / 128, 2);

  // ---- layer 1 ----
  k_cvt_pad<<<(N * FIN + 255) / 256, 256, 0, stream>>>(x, abuf, N, FIN, FIN);
  k_cvt_pad<<<(HCDIM * FIN + 255) / 256, 256, 0, stream>>>(Wl1, wl_b, HCDIM, FIN, FIN);
  k_cvt_pad<<<(HCDIM * FIN + 255) / 256, 256, 0, stream>>>(Wr1, wr_b, HCDIM, FIN, FIN);
  k_gemm_mfma<<<gemm_grid, 256, 0, stream>>>(abuf, wl_b, wr_b, bl1, br1,
                                             xl_b, xr_b, N, HCDIM, FIN);
  k_pre<<<AGGB, 256, 0, stream>>>(xl_b, xr_b, att1, pl, pr, N);
  k_agg<<<AGGB, 256, 0, stream>>>(xl_b, xr_b, pl, pr, csr_src, row_ptr, att1, b1, h, N);

  const int RPB = (N + 255) / 256;
  k_zero_f32<<<1, 2 * HCDIM, 0, stream>>>(colsum, 2 * HCDIM);
  k_bn_reduce<<<256, 320, 0, stream>>>(h, colsum, colsq, N, RPB);
  k_bn_apply_bf<<<N, KP2, 0, stream>>>(h, colsum, colsq, gamma, beta, abuf, N,
                                       1.f / (float)N);

  // ---- layer 2 ----
  k_cvt_pad<<<(HCDIM * KP2 + 255) / 256, 256, 0, stream>>>(Wl2, wl_b, HCDIM, HCDIM, KP2);
  k_cvt_pad<<<(HCDIM * KP2 + 255) / 256, 256, 0, stream>>>(Wr2, wr_b, HCDIM, HCDIM, KP2);
  k_gemm_mfma<<<gemm_grid, 256, 0, stream>>>(abuf, wl_b, wr_b, bl2, br2,
                                             xl_b, xr_b, N, HCDIM, KP2);
  k_pre<<<AGGB, 256, 0, stream>>>(xl_b, xr_b, att2, pl, pr, N);
  k_agg<<<AGGB, 256, 0, stream>>>(xl_b, xr_b, pl, pr, csr_src, row_ptr, att2, b2, h, N);

  k_zero_f32<<<1, 2 * HCDIM, 0, stream>>>(colsum, 2 * HCDIM);
  k_bn_reduce<<<256, 320, 0, stream>>>(h, colsum, colsq, N, RPB);
  k_bn_apply_f32<<<N, 320, 0, stream>>>(h, colsum, colsq, gamma, beta, N,
                                        1.f / (float)N);

  // ---- classifier ----
  k_classifier<<<AGGB, 256, 0, stream>>>(h, Wc, bc, out, N);
}

// Round 4
// 742.281 us; speedup vs baseline: 2.0937x; 1.1036x over previous
//
#include <hip/hip_runtime.h>

#define HCDIM 292
#define NHEAD 4
#define CDIM 73
#define SLOTS 5
#define KP2 320
#define BN_EPS 1e-5f

using u16x8 = __attribute__((ext_vector_type(8))) unsigned short;
using s16x8 = __attribute__((ext_vector_type(8))) short;   // 8 bf16 (4 VGPRs) MFMA frag
using f32x4 = __attribute__((ext_vector_type(4))) float;   // MFMA acc
using u16x4 = __attribute__((ext_vector_type(4))) unsigned short;

__device__ inline ushort f2bf(float f) {       // RTN-even fp32 -> bf16
  unsigned int u = __float_as_uint(f);
  u += 0x7FFFu + ((u >> 16) & 1u);
  return (ushort)(u >> 16);
}
__device__ inline float bf2f(ushort v) {
  return __uint_as_float(((unsigned int)v) << 16);
}

// ======================= utility =======================
__global__ void k_zero_i32(int* __restrict__ p, int n) {
  int i = blockIdx.x * blockDim.x + threadIdx.x;
  if (i < n) p[i] = 0;
}
__global__ void k_zero_f32(float* __restrict__ p, int n) {
  int i = blockIdx.x * blockDim.x + threadIdx.x;
  if (i < n) p[i] = 0.f;
}

// fp32 [rows,Kin] -> bf16 [rows,Kpad] zero-padded
__global__ void k_cvt_pad(const float* __restrict__ src, ushort* __restrict__ dst,
                          int rows, int Kin, int Kpad) {
  int i = blockIdx.x * blockDim.x + threadIdx.x;
  if (i >= rows * Kpad) return;
  int r = i / Kpad;
  int k = i - r * Kpad;
  dst[i] = (k < Kin) ? f2bf(src[(size_t)r * Kin + k]) : (ushort)0;
}

// ======================= CSR build =======================
__global__ void k_hist(const int* __restrict__ dst, int* __restrict__ deg, int E) {
  int i = blockIdx.x * blockDim.x + threadIdx.x;
  if (i < E) atomicAdd(&deg[dst[i]], 1);
}

__global__ __launch_bounds__(256) void k_block_sum(const int* __restrict__ deg,
                                                   int* __restrict__ bsum, int n) {
  __shared__ int s[256];
  int i = blockIdx.x * 256 + threadIdx.x;
  s[threadIdx.x] = (i < n) ? deg[i] : 0;
  __syncthreads();
  for (int off = 128; off > 0; off >>= 1) {
    if (threadIdx.x < off) s[threadIdx.x] += s[threadIdx.x + off];
    __syncthreads();
  }
  if (threadIdx.x == 0) bsum[blockIdx.x] = s[0];
}

__global__ __launch_bounds__(256) void k_scan_small(const int* __restrict__ bsum,
                                                    int* __restrict__ boff, int G) {
  __shared__ int s[256];
  int t = threadIdx.x;
  int v = (t < G) ? bsum[t] : 0;
  s[t] = v;
  __syncthreads();
  for (int off = 1; off < 256; off <<= 1) {
    int tv = (t >= off) ? s[t - off] : 0;
    __syncthreads();
    s[t] += tv;
    __syncthreads();
  }
  if (t < G) boff[t] = s[t] - v;
}

// scan + write row_ptr AND cursor; thread 0 of block 0 writes row_ptr[n]=E
__global__ __launch_bounds__(256) void k_scan_final(const int* __restrict__ deg,
                                                    const int* __restrict__ boff,
                                                    int* __restrict__ row_ptr,
                                                    int* __restrict__ cursor,
                                                    int n, int E) {
  __shared__ int s[256];
  int t = threadIdx.x;
  int i = blockIdx.x * 256 + t;
  int v = (i < n) ? deg[i] : 0;
  s[t] = v;
  __syncthreads();
  for (int off = 1; off < 256; off <<= 1) {
    int tv = (t >= off) ? s[t - off] : 0;
    __syncthreads();
    s[t] += tv;
    __syncthreads();
  }
  if (i < n) {
    int rp = boff[blockIdx.x] + s[t] - v;
    row_ptr[i] = rp;
    cursor[i] = rp;
  }
  if (i == 0) row_ptr[n] = E;
}

__global__ void k_csr_fill(const int* __restrict__ srcs, const int* __restrict__ dsts,
                           int* __restrict__ cursor, int* __restrict__ csr_src, int E) {
  int i = blockIdx.x * blockDim.x + threadIdx.x;
  if (i < E) {
    int pos = atomicAdd(&cursor[dsts[i]], 1);
    csr_src[pos] = srcs[i];
  }
}

// ======================= bf16 MFMA GEMM, permuted-split output =======================
// out{0,1} = bf16(A[M,Ks] @ W{0,1}[Nc,Ks]^T + bias) written as:
//   out4[gm][lane][kk] (lane=h*16+(c&15), kk=c>>4<4)   -- dense, 64 feats/head
//   out1[gm][lane]     (kk==4, c in [64,73))           -- 9 valid lanes/head
// where gn = h*73+c.
#define LDSK 40

__global__ __launch_bounds__(256) void k_gemm_mfma(
    const ushort* __restrict__ A, const ushort* __restrict__ W0,
    const ushort* __restrict__ W1, const float* __restrict__ b0,
    const float* __restrict__ b1, ushort* __restrict__ o4_0,
    ushort* __restrict__ o1_0, ushort* __restrict__ o4_1,
    ushort* __restrict__ o1_1, int M, int Nc, int Ks) {
  __shared__ ushort As[128 * LDSK];
  __shared__ ushort Bs[128 * LDSK];
  const ushort* W = blockIdx.z ? W1 : W0;
  const float* bias = blockIdx.z ? b1 : b0;
  ushort* out4 = blockIdx.z ? o4_1 : o4_0;
  ushort* out1 = blockIdx.z ? o1_1 : o1_0;
  const int bm = blockIdx.x * 128;
  const int bn = blockIdx.y * 128;
  const int tid = threadIdx.x;
  const int wave = tid >> 6, lane = tid & 63;
  const int quad = lane >> 4, lr = lane & 15;
  const int wm = (wave & 1) * 64, wn = (wave >> 1) * 64;

  f32x4 acc[4][4] = {};

  for (int k0 = 0; k0 < Ks; k0 += 32) {
#pragma unroll
    for (int part = 0; part < 2; ++part) {
      int e = tid + part * 256;
      int row = e >> 2;
      int kg = (e & 3) * 8;
      int gm = bm + row;
      u16x8 av = {};
      if (gm < M) av = *(const u16x8*)(A + (size_t)gm * Ks + k0 + kg);
      *(u16x8*)(As + row * LDSK + kg) = av;
      int gn = bn + row;
      u16x8 bv = {};
      if (gn < Nc) bv = *(const u16x8*)(W + (size_t)gn * Ks + k0 + kg);
      *(u16x8*)(Bs + row * LDSK + kg) = bv;
    }
    __syncthreads();
    s16x8 af[4], bf[4];
#pragma unroll
    for (int i = 0; i < 4; ++i) {
      af[i] = *(const s16x8*)(As + (wm + i * 16 + lr) * LDSK + quad * 8);
      bf[i] = *(const s16x8*)(Bs + (wn + i * 16 + lr) * LDSK + quad * 8);
    }
#pragma unroll
    for (int mi = 0; mi < 4; ++mi)
#pragma unroll
      for (int ni = 0; ni < 4; ++ni)
        acc[mi][ni] = __builtin_amdgcn_mfma_f32_16x16x32_bf16(af[mi], bf[ni],
                                                              acc[mi][ni], 0, 0, 0);
    __syncthreads();
  }

  // C/D layout: col = lane&15, row = quad*4 + reg
#pragma unroll
  for (int mi = 0; mi < 4; ++mi) {
#pragma unroll
    for (int r = 0; r < 4; ++r) {
      int gm = bm + wm + mi * 16 + quad * 4 + r;
      if (gm >= M) continue;
#pragma unroll
      for (int ni = 0; ni < 4; ++ni) {
        int gn = bn + wn + ni * 16 + lr;
        if (gn < Nc) {
          ushort val = f2bf(acc[mi][ni][r] + bias[gn]);
          int hh = gn / 73;
          int c = gn - hh * 73;
          int l2 = hh * 16 + (c & 15);
          int kk = c >> 4;
          if (kk < 4)
            out4[(size_t)gm * 256 + l2 * 4 + kk] = val;
          else
            out1[(size_t)gm * 64 + l2] = val;
        }
      }
    }
  }
}

// ======================= per-node attention pre-dots (permuted layout) =======================
__global__ __launch_bounds__(256) void k_pre(const ushort* __restrict__ xl4,
                                             const ushort* __restrict__ xl1,
                                             const ushort* __restrict__ xr4,
                                             const ushort* __restrict__ xr1,
                                             const float* __restrict__ att,
                                             float* __restrict__ pl,
                                             float* __restrict__ pr, int n) {
  int wave = threadIdx.x >> 6, lane = threadIdx.x & 63;
  int d = blockIdx.x * 4 + wave;
  if (d >= n) return;
  int hgrp = lane >> 4, li = lane & 15;
  int fbase = hgrp * CDIM + li;
  u16x4 a4 = *(const u16x4*)(xl4 + (size_t)d * 256 + lane * 4);
  u16x4 b4 = *(const u16x4*)(xr4 + (size_t)d * 256 + lane * 4);
  ushort a1 = xl1[(size_t)d * 64 + lane];
  ushort b1 = xr1[(size_t)d * 64 + lane];
  float Ta = 0.f, Tb = 0.f;
#pragma unroll
  for (int k = 0; k < 4; ++k) {
    float a = att[fbase + 16 * k];
    Ta = fmaf(bf2f(a4[k]), a, Ta);
    Tb = fmaf(bf2f(b4[k]), a, Tb);
  }
  {
    bool act = li < (CDIM - 64);   // li < 9
    float a = act ? att[fbase + 64] : 0.f;
    Ta = fmaf(bf2f(a1), a, Ta);
    Tb = fmaf(bf2f(b1), a, Tb);
  }
#pragma unroll
  for (int off = 1; off < 16; off <<= 1) {
    Ta += __shfl_xor(Ta, off, 64);
    Tb += __shfl_xor(Tb, off, 64);
  }
  if (li == 0) {
    pl[d * 4 + hgrp] = 0.6f * Ta;
    pr[d * 4 + hgrp] = 0.6f * Tb;
  }
}

// ======================= fused GATv2 attention (coalesced, pipelined) =======================
__global__ __launch_bounds__(256) void k_agg(const ushort* __restrict__ xl4,
                                             const ushort* __restrict__ xl1,
                                             const ushort* __restrict__ xr4,
                                             const ushort* __restrict__ xr1,
                                             const float* __restrict__ pl,
                                             const float* __restrict__ pr,
                                             const int* __restrict__ csr_src,
                                             const int* __restrict__ row_ptr,
                                             const float* __restrict__ att,
                                             const float* __restrict__ bvec,
                                             float* __restrict__ out, int n) {
  int wave = threadIdx.x >> 6, lane = threadIdx.x & 63;
  int d = blockIdx.x * 4 + wave;
  if (d >= n) return;
  int hgrp = lane >> 4, li = lane & 15;
  int start = __builtin_amdgcn_readfirstlane(row_ptr[d]);
  int end = __builtin_amdgcn_readfirstlane(row_ptr[d + 1]);

  int fbase = hgrp * CDIM + li;
  bool act4 = li < (CDIM - 64);                 // slot-4 validity
  int fi[SLOTS];
#pragma unroll
  for (int k = 0; k < 4; ++k) fi[k] = fbase + 16 * k;
  fi[4] = act4 ? fbase + 64 : fbase;            // clamped (att/bvec stay in-bounds)

  if (start >= end) {                            // isolated node: softmax of nothing -> bias
#pragma unroll
    for (int k = 0; k < 4; ++k) out[(size_t)d * HCDIM + fi[k]] = bvec[fi[k]];
    if (act4) out[(size_t)d * HCDIM + fi[4]] = bvec[fi[4]];
    return;
  }

  float xrv[SLOTS], attv[SLOTS], acc[SLOTS] = {};
  {
    u16x4 b4 = *(const u16x4*)(xr4 + (size_t)d * 256 + lane * 4);
#pragma unroll
    for (int k = 0; k < 4; ++k) {
      xrv[k] = bf2f(b4[k]);
      attv[k] = 0.4f * att[fi[k]];
    }
    xrv[4] = bf2f(xr1[(size_t)d * 64 + lane]);
    attv[4] = act4 ? 0.4f * att[fi[4]] : 0.f;
  }
  float prv = pr[d * 4 + hgrp];
  float den = 0.f;

  // 2-deep pipeline: idx prefetched 2 ahead (scalar), row data 1 ahead.
  int sA = __builtin_amdgcn_readfirstlane(csr_src[start]);
  int e1 = (start + 1 < end) ? start + 1 : end - 1;
  int sB = __builtin_amdgcn_readfirstlane(csr_src[e1]);
  u16x4 c4 = *(const u16x4*)(xl4 + (size_t)sA * 256 + lane * 4);
  ushort c1 = xl1[(size_t)sA * 64 + lane];
  float plA = pl[sA * 4 + hgrp];

  for (int e = start; e < end; ++e) {
    // prefetch next row (sB) + idx for e+2
    u16x4 n4 = *(const u16x4*)(xl4 + (size_t)sB * 256 + lane * 4);
    ushort n1 = xl1[(size_t)sB * 64 + lane];
    float plB = pl[sB * 4 + hgrp];
    int e2 = (e + 2 < end) ? e + 2 : end - 1;
    int sC = __builtin_amdgcn_readfirstlane(csr_src[e2]);

    // compute on current
    float xv[SLOTS] = {bf2f(c4[0]), bf2f(c4[1]), bf2f(c4[2]), bf2f(c4[3]), bf2f(c1)};
    float T = 0.f;
#pragma unroll
    for (int k = 0; k < SLOTS; ++k)
      T = fmaf(fabsf(xv[k] + xrv[k]), attv[k], T);
    T += __shfl_xor(T, 1, 64);
    T += __shfl_xor(T, 2, 64);
    T += __shfl_xor(T, 4, 64);
    T += __shfl_xor(T, 8, 64);
    float s = fminf(T + plA + prv, 60.f);
    float w = __expf(s);
    den += w;
#pragma unroll
    for (int k = 0; k < SLOTS; ++k) acc[k] = fmaf(w, xv[k], acc[k]);

    c4 = n4; c1 = n1; plA = plB; sB = sC;
  }

  float inv = 1.f / (den + 1e-16f);
#pragma unroll
  for (int k = 0; k < 4; ++k)
    out[(size_t)d * HCDIM + fi[k]] = fmaf(acc[k], inv, bvec[fi[k]]);
  if (act4)
    out[(size_t)d * HCDIM + fi[4]] = fmaf(acc[4], inv, bvec[fi[4]]);
}

// ======================= BatchNorm =======================
__global__ __launch_bounds__(320) void k_bn_reduce(const float* __restrict__ h,
                                                   float* __restrict__ colsum,
                                                   float* __restrict__ colsq,
                                                   int n, int rows_per_block) {
  int c = threadIdx.x;
  if (c >= HCDIM) return;
  int r0 = blockIdx.x * rows_per_block;
  int r1 = min(r0 + rows_per_block, n);
  float s = 0.f, s2 = 0.f;
  for (int r = r0; r < r1; ++r) {
    float v = h[(size_t)r * HCDIM + c];
    s += v;
    s2 += v * v;
  }
  atomicAdd(&colsum[c], s);
  atomicAdd(&colsq[c], s2);
}

// colsum/colsq -> scale/shift (in place): v_norm = h*scale + shift
__global__ void k_bn_coef(float* __restrict__ colsum, float* __restrict__ colsq,
                          const float* __restrict__ gamma,
                          const float* __restrict__ beta, float invN) {
  int c = threadIdx.x + blockIdx.x * blockDim.x;
  if (c >= HCDIM) return;
  float mu = colsum[c] * invN;
  float var = colsq[c] * invN - mu * mu;
  float scale = rsqrtf(var + BN_EPS) * gamma[c];
  colsum[c] = scale;
  colsq[c] = beta[c] - mu * scale;
}

// BN + leaky-relu, write bf16 zero-padded [n,KP2] (feeds layer-2 GEMM)
__global__ __launch_bounds__(320) void k_bn_apply_bf(
    const float* __restrict__ h, const float* __restrict__ scale,
    const float* __restrict__ shift, ushort* __restrict__ outb, int n) {
  int r = blockIdx.x, c = threadIdx.x;
  if (r >= n) return;
  ushort o = 0;
  if (c < HCDIM) {
    float v = fmaf(h[(size_t)r * HCDIM + c], scale[c], shift[c]);
    v = (v > 0.f) ? v : 0.01f * v;
    o = f2bf(v);
  }
  outb[(size_t)r * KP2 + c] = o;
}

// ======================= fused BN + leaky-relu + classifier =======================
__global__ __launch_bounds__(256) void k_bn_classifier(
    const float* __restrict__ h, const float* __restrict__ scale,
    const float* __restrict__ shift, const float* __restrict__ Wc,
    const float* __restrict__ bc, float* __restrict__ out, int n) {
  int wave = threadIdx.x >> 6, lane = threadIdx.x & 63;
  int r = blockIdx.x * 4 + wave;
  if (r >= n) return;
  float a0 = 0.f, a1 = 0.f;
#pragma unroll
  for (int k = 0; k < SLOTS; ++k) {
    int slot = lane + 64 * k;
    if (slot < HCDIM) {
      float v = fmaf(h[(size_t)r * HCDIM + slot], scale[slot], shift[slot]);
      v = (v > 0.f) ? v : 0.01f * v;
      a0 = fmaf(v, Wc[slot], a0);
      a1 = fmaf(v, Wc[HCDIM + slot], a1);
    }
  }
#pragma unroll
  for (int off = 32; off > 0; off >>= 1) {
    a0 += __shfl_xor(a0, off, 64);
    a1 += __shfl_xor(a1, off, 64);
  }
  if (lane == 0) {
    out[(size_t)2 * r] = a0 + bc[0];
    out[(size_t)2 * r + 1] = a1 + bc[1];
  }
}

// ======================= host launch =======================
extern "C" void kernel_launch(void* const* d_in, const int* in_sizes, int n_in,
                              void* d_out, int out_size, void* d_ws, size_t ws_size,
                              hipStream_t stream) {
  const float* x      = (const float*)d_in[0];
  const int*   eidx   = (const int*)d_in[1];
  const float* Wl1    = (const float*)d_in[2];
  const float* bl1    = (const float*)d_in[3];
  const float* Wr1    = (const float*)d_in[4];
  const float* br1    = (const float*)d_in[5];
  const float* att1   = (const float*)d_in[6];
  const float* b1     = (const float*)d_in[7];
  const float* Wl2    = (const float*)d_in[8];
  const float* bl2    = (const float*)d_in[9];
  const float* Wr2    = (const float*)d_in[10];
  const float* br2    = (const float*)d_in[11];
  const float* att2   = (const float*)d_in[12];
  const float* b2     = (const float*)d_in[13];
  const float* gamma  = (const float*)d_in[14];
  const float* beta   = (const float*)d_in[15];
  const float* Wc     = (const float*)d_in[16];
  const float* bc     = (const float*)d_in[17];
  float* out = (float*)d_out;

  const int FIN = 128;
  const int N = in_sizes[0] / FIN;   // 50000
  const int E = in_sizes[1] / 2;     // 800000
  const int NHC = N * HCDIM;

  const int* src = eidx;
  const int* dst = eidx + E;

  // ---- workspace layout (all 16B-aligned) ----
  float* h       = (float*)d_ws;                  // N*HCDIM f32
  ushort* xl4    = (ushort*)(h + NHC);            // N*256 bf16 (permuted slots 0-3)
  ushort* xl1    = xl4 + (size_t)N * 256;         // N*64  bf16 (permuted slot 4)
  ushort* xr4    = xl1 + (size_t)N * 64;          // N*256
  ushort* xr1    = xr4 + (size_t)N * 256;         // N*64
  ushort* abuf   = xr1 + (size_t)N * 64;          // N*KP2 bf16 (GEMM A input)
  ushort* wl_b   = abuf + (size_t)N * KP2;        // HCDIM*KP2
  ushort* wr_b   = wl_b + HCDIM * KP2;
  float* pl      = (float*)(wr_b + HCDIM * KP2);  // N*4
  float* pr      = pl + (size_t)N * NHEAD;        // N*4
  float* colsum  = pr + (size_t)N * NHEAD;        // HCDIM (-> scale)
  float* colsq   = colsum + HCDIM;                // HCDIM (-> shift)
  int* deg       = (int*)(colsq + HCDIM);
  int* row_ptr   = deg + N;                       // N+1
  int* cursor    = row_ptr + N + 1;
  int* bsum      = cursor + N;                    // 256
  int* boff      = bsum + 256;                    // 256
  int* csr_src   = boff + 256;                    // E

  const int G = (N + 255) / 256;
  const int EB = (E + 255) / 256;
  const int AGGB = (N + 3) / 4;

  // ---- CSR build ----
  k_zero_i32<<<G, 256, 0, stream>>>(deg, N);
  k_hist<<<EB, 256, 0, stream>>>(dst, deg, E);
  k_block_sum<<<G, 256, 0, stream>>>(deg, bsum, N);
  k_scan_small<<<1, 256, 0, stream>>>(bsum, boff, G);
  k_scan_final<<<G, 256, 0, stream>>>(deg, boff, row_ptr, cursor, N, E);
  k_csr_fill<<<EB, 256, 0, stream>>>(src, dst, cursor, csr_src, E);

  dim3 gemm_grid((N + 127) / 128, (HCDIM + 127) / 128, 2);

  // ---- layer 1 ----
  k_cvt_pad<<<(N * FIN + 255) / 256, 256, 0, stream>>>(x, abuf, N, FIN, FIN);
  k_cvt_pad<<<(HCDIM * FIN + 255) / 256, 256, 0, stream>>>(Wl1, wl_b, HCDIM, FIN, FIN);
  k_cvt_pad<<<(HCDIM * FIN + 255) / 256, 256, 0, stream>>>(Wr1, wr_b, HCDIM, FIN, FIN);
  k_gemm_mfma<<<gemm_grid, 256, 0, stream>>>(abuf, wl_b, wr_b, bl1, br1,
                                             xl4, xl1, xr4, xr1, N, HCDIM, FIN);
  k_pre<<<AGGB, 256, 0, stream>>>(xl4, xl1, xr4, xr1, att1, pl, pr, N);
  k_agg<<<AGGB, 256, 0, stream>>>(xl4, xl1, xr4, xr1, pl, pr, csr_src, row_ptr,
                                  att1, b1, h, N);

  const int RPB = (N + 255) / 256;
  k_zero_f32<<<1, 2 * HCDIM, 0, stream>>>(colsum, 2 * HCDIM);
  k_bn_reduce<<<256, 320, 0, stream>>>(h, colsum, colsq, N, RPB);
  k_bn_coef<<<2, 160, 0, stream>>>(colsum, colsq, gamma, beta, 1.f / (float)N);
  k_bn_apply_bf<<<N, KP2, 0, stream>>>(h, colsum, colsq, abuf, N);

  // ---- layer 2 ----
  k_cvt_pad<<<(HCDIM * KP2 + 255) / 256, 256, 0, stream>>>(Wl2, wl_b, HCDIM, HCDIM, KP2);
  k_cvt_pad<<<(HCDIM * KP2 + 255) / 256, 256, 0, stream>>>(Wr2, wr_b, HCDIM, HCDIM, KP2);
  k_gemm_mfma<<<gemm_grid, 256, 0, stream>>>(abuf, wl_b, wr_b, bl2, br2,
                                             xl4, xl1, xr4, xr1, N, HCDIM, KP2);
  k_pre<<<AGGB, 256, 0, stream>>>(xl4, xl1, xr4, xr1, att2, pl, pr, N);
  k_agg<<<AGGB, 256, 0, stream>>>(xl4, xl1, xr4, xr1, pl, pr, csr_src, row_ptr,
                                  att2, b2, h, N);

  k_zero_f32<<<1, 2 * HCDIM, 0, stream>>>(colsum, 2 * HCDIM);
  k_bn_reduce<<<256, 320, 0, stream>>>(h, colsum, colsq, N, RPB);
  k_bn_coef<<<2, 160, 0, stream>>>(colsum, colsq, gamma, beta, 1.f / (float)N);

  // ---- fused BN + classifier ----
  k_bn_classifier<<<AGGB, 256, 0, stream>>>(h, colsum, colsq, Wc, bc, out, N);
}

// Round 5
// 691.783 us; speedup vs baseline: 2.2466x; 1.0730x over previous
//
#include <hip/hip_runtime.h>

#define HCDIM 292
#define NHEAD 4
#define CDIM 73
#define SLOTS 5
#define KP2 320
#define NPERM 320
#define BN_EPS 1e-5f

using u16x8 = __attribute__((ext_vector_type(8))) unsigned short;
using s16x8 = __attribute__((ext_vector_type(8))) short;   // 8 bf16 (4 VGPRs) MFMA frag
using f32x4 = __attribute__((ext_vector_type(4))) float;   // MFMA acc
using u16x4 = __attribute__((ext_vector_type(4))) unsigned short;

__device__ inline ushort f2bf(float f) {       // RTN-even fp32 -> bf16
  unsigned int u = __float_as_uint(f);
  u += 0x7FFFu + ((u >> 16) & 1u);
  return (ushort)(u >> 16);
}
__device__ inline float bf2f(ushort v) {
  return __uint_as_float(((unsigned int)v) << 16);
}

// ======================= utility =======================
__global__ void k_zero_i32(int* __restrict__ p, int n) {
  int i = blockIdx.x * blockDim.x + threadIdx.x;
  if (i < n) p[i] = 0;
}
__global__ void k_zero_f32(float* __restrict__ p, int n) {
  int i = blockIdx.x * blockDim.x + threadIdx.x;
  if (i < n) p[i] = 0.f;
}

// fp32 [rows,Kin] -> bf16 [rows,Kpad] zero-padded
__global__ void k_cvt_pad(const float* __restrict__ src, ushort* __restrict__ dst,
                          int rows, int Kin, int Kpad) {
  int i = blockIdx.x * blockDim.x + threadIdx.x;
  if (i >= rows * Kpad) return;
  int r = i / Kpad;
  int k = i - r * Kpad;
  dst[i] = (k < Kin) ? f2bf(src[(size_t)r * Kin + k]) : (ushort)0;
}

// permuted weight prep: Wp[p][Kpad] bf16, p in agg-lane order; pb[p] bias.
// p<256: h=p>>6, c=(p&3)*16 + ((p>>2)&15). p>=256: q=p-256, h=q>>4, c=64+(q&15), valid iff (q&15)<9.
__global__ void k_wperm(const float* __restrict__ W, const float* __restrict__ b,
                        ushort* __restrict__ Wp, float* __restrict__ pb,
                        int Kin, int Kpad) {
  int p = blockIdx.x;
  int t = threadIdx.x;
  int h, c;
  bool valid;
  if (p < 256) {
    h = p >> 6;
    c = ((p & 3) << 4) | ((p >> 2) & 15);
    valid = true;
  } else {
    int q = p - 256;
    h = q >> 4;
    c = 64 + (q & 15);
    valid = (q & 15) < (CDIM - 64);
  }
  int gn = h * CDIM + c;
  ushort v = 0;
  if (valid && t < Kin) v = f2bf(W[(size_t)gn * Kin + t]);
  Wp[(size_t)p * Kpad + t] = v;
  if (t == 0) pb[p] = valid ? b[gn] : 0.f;
}

// ======================= CSR build =======================
__global__ void k_hist(const int* __restrict__ dst, int* __restrict__ deg, int E) {
  int i = blockIdx.x * blockDim.x + threadIdx.x;
  if (i < E) atomicAdd(&deg[dst[i]], 1);
}

__global__ __launch_bounds__(256) void k_block_sum(const int* __restrict__ deg,
                                                   int* __restrict__ bsum, int n) {
  __shared__ int s[256];
  int i = blockIdx.x * 256 + threadIdx.x;
  s[threadIdx.x] = (i < n) ? deg[i] : 0;
  __syncthreads();
  for (int off = 128; off > 0; off >>= 1) {
    if (threadIdx.x < off) s[threadIdx.x] += s[threadIdx.x + off];
    __syncthreads();
  }
  if (threadIdx.x == 0) bsum[blockIdx.x] = s[0];
}

__global__ __launch_bounds__(256) void k_scan_small(const int* __restrict__ bsum,
                                                    int* __restrict__ boff, int G) {
  __shared__ int s[256];
  int t = threadIdx.x;
  int v = (t < G) ? bsum[t] : 0;
  s[t] = v;
  __syncthreads();
  for (int off = 1; off < 256; off <<= 1) {
    int tv = (t >= off) ? s[t - off] : 0;
    __syncthreads();
    s[t] += tv;
    __syncthreads();
  }
  if (t < G) boff[t] = s[t] - v;
}

__global__ __launch_bounds__(256) void k_scan_final(const int* __restrict__ deg,
                                                    const int* __restrict__ boff,
                                                    int* __restrict__ row_ptr,
                                                    int* __restrict__ cursor,
                                                    int n, int E) {
  __shared__ int s[256];
  int t = threadIdx.x;
  int i = blockIdx.x * 256 + t;
  int v = (i < n) ? deg[i] : 0;
  s[t] = v;
  __syncthreads();
  for (int off = 1; off < 256; off <<= 1) {
    int tv = (t >= off) ? s[t - off] : 0;
    __syncthreads();
    s[t] += tv;
    __syncthreads();
  }
  if (i < n) {
    int rp = boff[blockIdx.x] + s[t] - v;
    row_ptr[i] = rp;
    cursor[i] = rp;
  }
  if (i == 0) row_ptr[n] = E;
}

__global__ void k_csr_fill(const int* __restrict__ srcs, const int* __restrict__ dsts,
                           int* __restrict__ cursor, int* __restrict__ csr_src, int E) {
  int i = blockIdx.x * blockDim.x + threadIdx.x;
  if (i < E) {
    int pos = atomicAdd(&cursor[dsts[i]], 1);
    csr_src[pos] = srcs[i];
  }
}

// ======================= bf16 MFMA GEMM, permuted weights =======================
// out = bf16(A[M,Ks] @ Wp[320,Ks]^T + pb), written [M][320] contiguous (agg-lane order).
// Tile 128M x 160N, BK=32, 4 waves (2x2), wave tile 64x80 (4x5 frags).
#define LDSK 40

__global__ __launch_bounds__(256) void k_gemm_mfma(
    const ushort* __restrict__ A, const ushort* __restrict__ Wp0,
    const ushort* __restrict__ Wp1, const float* __restrict__ pb0,
    const float* __restrict__ pb1, ushort* __restrict__ o0,
    ushort* __restrict__ o1, int M, int Ks) {
  __shared__ ushort As[128 * LDSK];
  __shared__ ushort Bs[160 * LDSK];
  const ushort* W = blockIdx.z ? Wp1 : Wp0;
  const float* pb = blockIdx.z ? pb1 : pb0;
  ushort* out = blockIdx.z ? o1 : o0;
  const int bm = blockIdx.x * 128;
  const int bn = blockIdx.y * 160;
  const int tid = threadIdx.x;
  const int wave = tid >> 6, lane = tid & 63;
  const int quad = lane >> 4, lr = lane & 15;
  const int wm = (wave & 1) * 64, wn = (wave >> 1) * 80;

  f32x4 acc[4][5] = {};

  for (int k0 = 0; k0 < Ks; k0 += 32) {
    // stage A: 128 rows x 32k = 512 u16x8 slots
#pragma unroll
    for (int part = 0; part < 2; ++part) {
      int e = tid + part * 256;
      int row = e >> 2, kg = (e & 3) * 8;
      int gm = bm + row;
      u16x8 av = {};
      if (gm < M) av = *(const u16x8*)(A + (size_t)gm * Ks + k0 + kg);
      *(u16x8*)(As + row * LDSK + kg) = av;
    }
    // stage B: 160 rows x 32k = 640 slots
#pragma unroll
    for (int part = 0; part < 3; ++part) {
      int e = tid + part * 256;
      if (e < 640) {
        int row = e >> 2, kg = (e & 3) * 8;
        *(u16x8*)(Bs + row * LDSK + kg) =
            *(const u16x8*)(W + (size_t)(bn + row) * Ks + k0 + kg);
      }
    }
    __syncthreads();
    s16x8 af[4], bf[5];
#pragma unroll
    for (int i = 0; i < 4; ++i)
      af[i] = *(const s16x8*)(As + (wm + i * 16 + lr) * LDSK + quad * 8);
#pragma unroll
    for (int i = 0; i < 5; ++i)
      bf[i] = *(const s16x8*)(Bs + (wn + i * 16 + lr) * LDSK + quad * 8);
#pragma unroll
    for (int mi = 0; mi < 4; ++mi)
#pragma unroll
      for (int ni = 0; ni < 5; ++ni)
        acc[mi][ni] = __builtin_amdgcn_mfma_f32_16x16x32_bf16(af[mi], bf[ni],
                                                              acc[mi][ni], 0, 0, 0);
    __syncthreads();
  }

  float pbv[5];
#pragma unroll
  for (int ni = 0; ni < 5; ++ni) pbv[ni] = pb[bn + wn + ni * 16 + lr];

  // C/D layout: col = lane&15, row = quad*4 + reg
#pragma unroll
  for (int mi = 0; mi < 4; ++mi) {
#pragma unroll
    for (int r = 0; r < 4; ++r) {
      int gm = bm + wm + mi * 16 + quad * 4 + r;
      if (gm >= M) continue;
#pragma unroll
      for (int ni = 0; ni < 5; ++ni) {
        int gn = bn + wn + ni * 16 + lr;
        out[(size_t)gm * NPERM + gn] = f2bf(acc[mi][ni][r] + pbv[ni]);
      }
    }
  }
}

// ======================= per-node attention pre-dots (permuted layout) =======================
__global__ __launch_bounds__(256) void k_pre(const ushort* __restrict__ xl,
                                             const ushort* __restrict__ xr,
                                             const float* __restrict__ att,
                                             float* __restrict__ pl,
                                             float* __restrict__ pr, int n) {
  int wave = threadIdx.x >> 6, lane = threadIdx.x & 63;
  int d = blockIdx.x * 4 + wave;
  if (d >= n) return;
  int hgrp = lane >> 4, li = lane & 15;
  int fbase = hgrp * CDIM + li;
  u16x4 a4 = *(const u16x4*)(xl + (size_t)d * NPERM + lane * 4);
  u16x4 b4 = *(const u16x4*)(xr + (size_t)d * NPERM + lane * 4);
  ushort a1 = xl[(size_t)d * NPERM + 256 + lane];
  ushort b1 = xr[(size_t)d * NPERM + 256 + lane];
  float Ta = 0.f, Tb = 0.f;
#pragma unroll
  for (int k = 0; k < 4; ++k) {
    float a = att[fbase + 16 * k];
    Ta = fmaf(bf2f(a4[k]), a, Ta);
    Tb = fmaf(bf2f(b4[k]), a, Tb);
  }
  {
    bool act = li < (CDIM - 64);   // li < 9
    float a = act ? att[fbase + 64] : 0.f;
    Ta = fmaf(bf2f(a1), a, Ta);
    Tb = fmaf(bf2f(b1), a, Tb);
  }
#pragma unroll
  for (int off = 1; off < 16; off <<= 1) {
    Ta += __shfl_xor(Ta, off, 64);
    Tb += __shfl_xor(Tb, off, 64);
  }
  if (li == 0) {
    pl[d * 4 + hgrp] = 0.6f * Ta;
    pr[d * 4 + hgrp] = 0.6f * Tb;
  }
}

// ======================= fused GATv2 attention (coalesced, pipelined) =======================
__global__ __launch_bounds__(256) void k_agg(const ushort* __restrict__ xl,
                                             const ushort* __restrict__ xr,
                                             const float* __restrict__ pl,
                                             const float* __restrict__ pr,
                                             const int* __restrict__ csr_src,
                                             const int* __restrict__ row_ptr,
                                             const float* __restrict__ att,
                                             const float* __restrict__ bvec,
                                             float* __restrict__ out, int n) {
  int wave = threadIdx.x >> 6, lane = threadIdx.x & 63;
  int d = blockIdx.x * 4 + wave;
  if (d >= n) return;
  int hgrp = lane >> 4, li = lane & 15;
  int start = __builtin_amdgcn_readfirstlane(row_ptr[d]);
  int end = __builtin_amdgcn_readfirstlane(row_ptr[d + 1]);

  int fbase = hgrp * CDIM + li;
  bool act4 = li < (CDIM - 64);
  int fi[SLOTS];
#pragma unroll
  for (int k = 0; k < 4; ++k) fi[k] = fbase + 16 * k;
  fi[4] = act4 ? fbase + 64 : fbase;

  if (start >= end) {                            // isolated node -> bias only
#pragma unroll
    for (int k = 0; k < 4; ++k) out[(size_t)d * HCDIM + fi[k]] = bvec[fi[k]];
    if (act4) out[(size_t)d * HCDIM + fi[4]] = bvec[fi[4]];
    return;
  }

  float xrv[SLOTS], attv[SLOTS], acc[SLOTS] = {};
  {
    u16x4 b4 = *(const u16x4*)(xr + (size_t)d * NPERM + lane * 4);
#pragma unroll
    for (int k = 0; k < 4; ++k) {
      xrv[k] = bf2f(b4[k]);
      attv[k] = 0.4f * att[fi[k]];
    }
    xrv[4] = bf2f(xr[(size_t)d * NPERM + 256 + lane]);
    attv[4] = act4 ? 0.4f * att[fi[4]] : 0.f;
  }
  float prv = pr[d * 4 + hgrp];
  float den = 0.f;

  // 2-deep pipeline
  int sA = __builtin_amdgcn_readfirstlane(csr_src[start]);
  int e1 = (start + 1 < end) ? start + 1 : end - 1;
  int sB = __builtin_amdgcn_readfirstlane(csr_src[e1]);
  u16x4 c4 = *(const u16x4*)(xl + (size_t)sA * NPERM + lane * 4);
  ushort c1 = xl[(size_t)sA * NPERM + 256 + lane];
  float plA = pl[sA * 4 + hgrp];

  for (int e = start; e < end; ++e) {
    u16x4 n4 = *(const u16x4*)(xl + (size_t)sB * NPERM + lane * 4);
    ushort n1 = xl[(size_t)sB * NPERM + 256 + lane];
    float plB = pl[sB * 4 + hgrp];
    int e2 = (e + 2 < end) ? e + 2 : end - 1;
    int sC = __builtin_amdgcn_readfirstlane(csr_src[e2]);

    float xv[SLOTS] = {bf2f(c4[0]), bf2f(c4[1]), bf2f(c4[2]), bf2f(c4[3]), bf2f(c1)};
    float T = 0.f;
#pragma unroll
    for (int k = 0; k < SLOTS; ++k)
      T = fmaf(fabsf(xv[k] + xrv[k]), attv[k], T);
    T += __shfl_xor(T, 1, 64);
    T += __shfl_xor(T, 2, 64);
    T += __shfl_xor(T, 4, 64);
    T += __shfl_xor(T, 8, 64);
    float s = fminf(T + plA + prv, 60.f);
    float w = __expf(s);
    den += w;
#pragma unroll
    for (int k = 0; k < SLOTS; ++k) acc[k] = fmaf(w, xv[k], acc[k]);

    c4 = n4; c1 = n1; plA = plB; sB = sC;
  }

  float inv = 1.f / (den + 1e-16f);
#pragma unroll
  for (int k = 0; k < 4; ++k)
    out[(size_t)d * HCDIM + fi[k]] = fmaf(acc[k], inv, bvec[fi[k]]);
  if (act4)
    out[(size_t)d * HCDIM + fi[4]] = fmaf(acc[4], inv, bvec[fi[4]]);
}

// ======================= BatchNorm =======================
__global__ __launch_bounds__(320) void k_bn_reduce(const float* __restrict__ h,
                                                   float* __restrict__ colsum,
                                                   float* __restrict__ colsq,
                                                   int n, int rows_per_block) {
  int c = threadIdx.x;
  if (c >= HCDIM) return;
  int r0 = blockIdx.x * rows_per_block;
  int r1 = min(r0 + rows_per_block, n);
  float s = 0.f, s2 = 0.f;
  for (int r = r0; r < r1; ++r) {
    float v = h[(size_t)r * HCDIM + c];
    s += v;
    s2 += v * v;
  }
  atomicAdd(&colsum[c], s);
  atomicAdd(&colsq[c], s2);
}

__global__ void k_bn_coef(float* __restrict__ colsum, float* __restrict__ colsq,
                          const float* __restrict__ gamma,
                          const float* __restrict__ beta, float invN) {
  int c = threadIdx.x + blockIdx.x * blockDim.x;
  if (c >= HCDIM) return;
  float mu = colsum[c] * invN;
  float var = colsq[c] * invN - mu * mu;
  float scale = rsqrtf(var + BN_EPS) * gamma[c];
  colsum[c] = scale;
  colsq[c] = beta[c] - mu * scale;
}

__global__ __launch_bounds__(320) void k_bn_apply_bf(
    const float* __restrict__ h, const float* __restrict__ scale,
    const float* __restrict__ shift, ushort* __restrict__ outb, int n) {
  int r = blockIdx.x, c = threadIdx.x;
  if (r >= n) return;
  ushort o = 0;
  if (c < HCDIM) {
    float v = fmaf(h[(size_t)r * HCDIM + c], scale[c], shift[c]);
    v = (v > 0.f) ? v : 0.01f * v;
    o = f2bf(v);
  }
  outb[(size_t)r * KP2 + c] = o;
}

// ======================= fused BN + leaky-relu + classifier =======================
__global__ __launch_bounds__(256) void k_bn_classifier(
    const float* __restrict__ h, const float* __restrict__ scale,
    const float* __restrict__ shift, const float* __restrict__ Wc,
    const float* __restrict__ bc, float* __restrict__ out, int n) {
  int wave = threadIdx.x >> 6, lane = threadIdx.x & 63;
  int r = blockIdx.x * 4 + wave;
  if (r >= n) return;
  float a0 = 0.f, a1 = 0.f;
#pragma unroll
  for (int k = 0; k < SLOTS; ++k) {
    int slot = lane + 64 * k;
    if (slot < HCDIM) {
      float v = fmaf(h[(size_t)r * HCDIM + slot], scale[slot], shift[slot]);
      v = (v > 0.f) ? v : 0.01f * v;
      a0 = fmaf(v, Wc[slot], a0);
      a1 = fmaf(v, Wc[HCDIM + slot], a1);
    }
  }
#pragma unroll
  for (int off = 32; off > 0; off >>= 1) {
    a0 += __shfl_xor(a0, off, 64);
    a1 += __shfl_xor(a1, off, 64);
  }
  if (lane == 0) {
    out[(size_t)2 * r] = a0 + bc[0];
    out[(size_t)2 * r + 1] = a1 + bc[1];
  }
}

// ======================= host launch =======================
extern "C" void kernel_launch(void* const* d_in, const int* in_sizes, int n_in,
                              void* d_out, int out_size, void* d_ws, size_t ws_size,
                              hipStream_t stream) {
  const float* x      = (const float*)d_in[0];
  const int*   eidx   = (const int*)d_in[1];
  const float* Wl1    = (const float*)d_in[2];
  const float* bl1    = (const float*)d_in[3];
  const float* Wr1    = (const float*)d_in[4];
  const float* br1    = (const float*)d_in[5];
  const float* att1   = (const float*)d_in[6];
  const float* b1     = (const float*)d_in[7];
  const float* Wl2    = (const float*)d_in[8];
  const float* bl2    = (const float*)d_in[9];
  const float* Wr2    = (const float*)d_in[10];
  const float* br2    = (const float*)d_in[11];
  const float* att2   = (const float*)d_in[12];
  const float* b2     = (const float*)d_in[13];
  const float* gamma  = (const float*)d_in[14];
  const float* beta   = (const float*)d_in[15];
  const float* Wc     = (const float*)d_in[16];
  const float* bc     = (const float*)d_in[17];
  float* out = (float*)d_out;

  const int FIN = 128;
  const int N = in_sizes[0] / FIN;   // 50000
  const int E = in_sizes[1] / 2;     // 800000
  const int NHC = N * HCDIM;

  const int* src = eidx;
  const int* dst = eidx + E;

  // ---- workspace layout (16B-aligned) ----
  float* h       = (float*)d_ws;                  // N*HCDIM f32
  ushort* xl     = (ushort*)(h + NHC);            // N*320 bf16 (permuted)
  ushort* xr     = xl + (size_t)N * NPERM;        // N*320
  ushort* abuf   = xr + (size_t)N * NPERM;        // N*KP2 bf16 (GEMM A input)
  ushort* wl_p   = abuf + (size_t)N * KP2;        // 320*320
  ushort* wr_p   = wl_p + NPERM * KP2;            // 320*320
  float* pbl     = (float*)(wr_p + NPERM * KP2);  // 320
  float* pbr     = pbl + NPERM;                   // 320
  float* pl      = pbr + NPERM;                   // N*4
  float* pr      = pl + (size_t)N * NHEAD;        // N*4
  float* colsum  = pr + (size_t)N * NHEAD;        // HCDIM (-> scale)
  float* colsq   = colsum + HCDIM;                // HCDIM (-> shift)
  int* deg       = (int*)(colsq + HCDIM);
  int* row_ptr   = deg + N;                       // N+1
  int* cursor    = row_ptr + N + 1;
  int* bsum      = cursor + N;                    // 256
  int* boff      = bsum + 256;                    // 256
  int* csr_src   = boff + 256;                    // E

  const int G = (N + 255) / 256;
  const int EB = (E + 255) / 256;
  const int AGGB = (N + 3) / 4;

  // ---- CSR build ----
  k_zero_i32<<<G, 256, 0, stream>>>(deg, N);
  k_hist<<<EB, 256, 0, stream>>>(dst, deg, E);
  k_block_sum<<<G, 256, 0, stream>>>(deg, bsum, N);
  k_scan_small<<<1, 256, 0, stream>>>(bsum, boff, G);
  k_scan_final<<<G, 256, 0, stream>>>(deg, boff, row_ptr, cursor, N, E);
  k_csr_fill<<<EB, 256, 0, stream>>>(src, dst, cursor, csr_src, E);

  dim3 gemm_grid((N + 127) / 128, 2, 2);

  // ---- layer 1 ----
  k_cvt_pad<<<(N * FIN + 255) / 256, 256, 0, stream>>>(x, abuf, N, FIN, FIN);
  k_wperm<<<NPERM, FIN, 0, stream>>>(Wl1, bl1, wl_p, pbl, FIN, FIN);
  k_wperm<<<NPERM, FIN, 0, stream>>>(Wr1, br1, wr_p, pbr, FIN, FIN);
  k_gemm_mfma<<<gemm_grid, 256, 0, stream>>>(abuf, wl_p, wr_p, pbl, pbr,
                                             xl, xr, N, FIN);
  k_pre<<<AGGB, 256, 0, stream>>>(xl, xr, att1, pl, pr, N);
  k_agg<<<AGGB, 256, 0, stream>>>(xl, xr, pl, pr, csr_src, row_ptr, att1, b1, h, N);

  const int RPB = (N + 255) / 256;
  k_zero_f32<<<1, 2 * HCDIM, 0, stream>>>(colsum, 2 * HCDIM);
  k_bn_reduce<<<256, 320, 0, stream>>>(h, colsum, colsq, N, RPB);
  k_bn_coef<<<2, 160, 0, stream>>>(colsum, colsq, gamma, beta, 1.f / (float)N);
  k_bn_apply_bf<<<N, KP2, 0, stream>>>(h, colsum, colsq, abuf, N);

  // ---- layer 2 ----
  k_wperm<<<NPERM, KP2, 0, stream>>>(Wl2, bl2, wl_p, pbl, HCDIM, KP2);
  k_wperm<<<NPERM, KP2, 0, stream>>>(Wr2, br2, wr_p, pbr, HCDIM, KP2);
  k_gemm_mfma<<<gemm_grid, 256, 0, stream>>>(abuf, wl_p, wr_p, pbl, pbr,
                                             xl, xr, N, KP2);
  k_pre<<<AGGB, 256, 0, stream>>>(xl, xr, att2, pl, pr, N);
  k_agg<<<AGGB, 256, 0, stream>>>(xl, xr, pl, pr, csr_src, row_ptr, att2, b2, h, N);

  k_zero_f32<<<1, 2 * HCDIM, 0, stream>>>(colsum, 2 * HCDIM);
  k_bn_reduce<<<256, 320, 0, stream>>>(h, colsum, colsq, N, RPB);
  k_bn_coef<<<2, 160, 0, stream>>>(colsum, colsq, gamma, beta, 1.f / (float)N);

  // ---- fused BN + classifier ----
  k_bn_classifier<<<AGGB, 256, 0, stream>>>(h, colsum, colsq, Wc, bc, out, N);
}

// Round 6
// 675.247 us; speedup vs baseline: 2.3016x; 1.0245x over previous
//
#include <hip/hip_runtime.h>

#define HCDIM 292
#define NHEAD 4
#define CDIM 73
#define SLOTS 5
#define KP2 320
#define NPERM 320
#define BN_EPS 1e-5f

using u16x8 = __attribute__((ext_vector_type(8))) unsigned short;
using s16x8 = __attribute__((ext_vector_type(8))) short;   // 8 bf16 (4 VGPRs) MFMA frag
using f32x4 = __attribute__((ext_vector_type(4))) float;   // MFMA acc
using u16x4 = __attribute__((ext_vector_type(4))) unsigned short;

__device__ inline ushort f2bf(float f) {       // RTN-even fp32 -> bf16
  unsigned int u = __float_as_uint(f);
  u += 0x7FFFu + ((u >> 16) & 1u);
  return (ushort)(u >> 16);
}
__device__ inline float bf2f(ushort v) {
  return __uint_as_float(((unsigned int)v) << 16);
}

// ======================= utility =======================
__global__ void k_zero_i32(int* __restrict__ p, int n) {
  int i = blockIdx.x * blockDim.x + threadIdx.x;
  if (i < n) p[i] = 0;
}
__global__ void k_zero_f32(float* __restrict__ p, int n) {
  int i = blockIdx.x * blockDim.x + threadIdx.x;
  if (i < n) p[i] = 0.f;
}

// fp32 [rows,Kin] -> bf16 [rows,Kpad] zero-padded
__global__ void k_cvt_pad(const float* __restrict__ src, ushort* __restrict__ dst,
                          int rows, int Kin, int Kpad) {
  int i = blockIdx.x * blockDim.x + threadIdx.x;
  if (i >= rows * Kpad) return;
  int r = i / Kpad;
  int k = i - r * Kpad;
  dst[i] = (k < Kin) ? f2bf(src[(size_t)r * Kin + k]) : (ushort)0;
}

// permuted weight prep: Wp[p][Kpad] bf16, p in agg-lane order; pb[p] bias.
__global__ void k_wperm(const float* __restrict__ W, const float* __restrict__ b,
                        ushort* __restrict__ Wp, float* __restrict__ pb,
                        int Kin, int Kpad) {
  int p = blockIdx.x;
  int t = threadIdx.x;
  int h, c;
  bool valid;
  if (p < 256) {
    h = p >> 6;
    c = ((p & 3) << 4) | ((p >> 2) & 15);
    valid = true;
  } else {
    int q = p - 256;
    h = q >> 4;
    c = 64 + (q & 15);
    valid = (q & 15) < (CDIM - 64);
  }
  int gn = h * CDIM + c;
  ushort v = 0;
  if (valid && t < Kin) v = f2bf(W[(size_t)gn * Kin + t]);
  Wp[(size_t)p * Kpad + t] = v;
  if (t == 0) pb[p] = valid ? b[gn] : 0.f;
}

// ======================= CSR build =======================
__global__ void k_hist(const int* __restrict__ dst, int* __restrict__ deg, int E) {
  int i = blockIdx.x * blockDim.x + threadIdx.x;
  if (i < E) atomicAdd(&deg[dst[i]], 1);
}

__global__ __launch_bounds__(256) void k_block_sum(const int* __restrict__ deg,
                                                   int* __restrict__ bsum, int n) {
  __shared__ int s[256];
  int i = blockIdx.x * 256 + threadIdx.x;
  s[threadIdx.x] = (i < n) ? deg[i] : 0;
  __syncthreads();
  for (int off = 128; off > 0; off >>= 1) {
    if (threadIdx.x < off) s[threadIdx.x] += s[threadIdx.x + off];
    __syncthreads();
  }
  if (threadIdx.x == 0) bsum[blockIdx.x] = s[0];
}

__global__ __launch_bounds__(256) void k_scan_small(const int* __restrict__ bsum,
                                                    int* __restrict__ boff, int G) {
  __shared__ int s[256];
  int t = threadIdx.x;
  int v = (t < G) ? bsum[t] : 0;
  s[t] = v;
  __syncthreads();
  for (int off = 1; off < 256; off <<= 1) {
    int tv = (t >= off) ? s[t - off] : 0;
    __syncthreads();
    s[t] += tv;
    __syncthreads();
  }
  if (t < G) boff[t] = s[t] - v;
}

__global__ __launch_bounds__(256) void k_scan_final(const int* __restrict__ deg,
                                                    const int* __restrict__ boff,
                                                    int* __restrict__ row_ptr,
                                                    int* __restrict__ cursor,
                                                    int n, int E) {
  __shared__ int s[256];
  int t = threadIdx.x;
  int i = blockIdx.x * 256 + t;
  int v = (i < n) ? deg[i] : 0;
  s[t] = v;
  __syncthreads();
  for (int off = 1; off < 256; off <<= 1) {
    int tv = (t >= off) ? s[t - off] : 0;
    __syncthreads();
    s[t] += tv;
    __syncthreads();
  }
  if (i < n) {
    int rp = boff[blockIdx.x] + s[t] - v;
    row_ptr[i] = rp;
    cursor[i] = rp;
  }
  if (i == 0) row_ptr[n] = E;
}

__global__ void k_csr_fill(const int* __restrict__ srcs, const int* __restrict__ dsts,
                           int* __restrict__ cursor, int* __restrict__ csr_src, int E) {
  int i = blockIdx.x * blockDim.x + threadIdx.x;
  if (i < E) {
    int pos = atomicAdd(&cursor[dsts[i]], 1);
    csr_src[pos] = srcs[i];
  }
}

// ======================= bf16 MFMA GEMM, combined 640-col weights =======================
// grid (4, mtiles): blockIdx.x = column-tile (fastest -> A-tile shared in L2/L3).
// ct<2 -> xl cols [ct*160,+160); ct>=2 -> xr cols [(ct-2)*160,+160).
// Tile 128M x 160N, BK=64 (40 MFMA / barrier), 4 waves (2x2), wave 64x80.
#define LDSK 72   // 64 + 8 pad: frag-read bank stride 4 dwords -> 2-way only (free)

__global__ __launch_bounds__(256) void k_gemm_mfma(
    const ushort* __restrict__ A, const ushort* __restrict__ Wb,
    const float* __restrict__ pb, ushort* __restrict__ o0,
    ushort* __restrict__ o1, int M, int Ks) {
  __shared__ ushort As[128 * LDSK];
  __shared__ ushort Bs[160 * LDSK];
  const int ct = blockIdx.x;
  const int bm = blockIdx.y * 128;
  ushort* out = (ct < 2) ? o0 : o1;
  const int colbase = (ct & 1) * 160;
  const int wrow0 = ct * 160;
  const int tid = threadIdx.x;
  const int wave = tid >> 6, lane = tid & 63;
  const int quad = lane >> 4, lr = lane & 15;
  const int wm = (wave & 1) * 64, wn = (wave >> 1) * 80;

  f32x4 acc[4][5] = {};

  for (int k0 = 0; k0 < Ks; k0 += 64) {
    // stage A: 128 rows x 64 k = 1024 u16x8 slots (4/thread)
#pragma unroll
    for (int part = 0; part < 4; ++part) {
      int e = tid + part * 256;
      int row = e >> 3, kg = (e & 7) * 8;
      int gm = bm + row;
      u16x8 av = {};
      if (gm < M) av = *(const u16x8*)(A + (size_t)gm * Ks + k0 + kg);
      *(u16x8*)(As + row * LDSK + kg) = av;
    }
    // stage B: 160 rows x 64 k = 1280 slots (5/thread)
#pragma unroll
    for (int part = 0; part < 5; ++part) {
      int e = tid + part * 256;
      int row = e >> 3, kg = (e & 7) * 8;
      *(u16x8*)(Bs + row * LDSK + kg) =
          *(const u16x8*)(Wb + (size_t)(wrow0 + row) * Ks + k0 + kg);
    }
    __syncthreads();
#pragma unroll
    for (int kh = 0; kh < 2; ++kh) {
      s16x8 af[4], bf[5];
#pragma unroll
      for (int i = 0; i < 4; ++i)
        af[i] = *(const s16x8*)(As + (wm + i * 16 + lr) * LDSK + kh * 32 + quad * 8);
#pragma unroll
      for (int i = 0; i < 5; ++i)
        bf[i] = *(const s16x8*)(Bs + (wn + i * 16 + lr) * LDSK + kh * 32 + quad * 8);
#pragma unroll
      for (int mi = 0; mi < 4; ++mi)
#pragma unroll
        for (int ni = 0; ni < 5; ++ni)
          acc[mi][ni] = __builtin_amdgcn_mfma_f32_16x16x32_bf16(af[mi], bf[ni],
                                                                acc[mi][ni], 0, 0, 0);
    }
    __syncthreads();
  }

  float pbv[5];
#pragma unroll
  for (int ni = 0; ni < 5; ++ni) pbv[ni] = pb[wrow0 + wn + ni * 16 + lr];

  // C/D layout: col = lane&15, row = quad*4 + reg
#pragma unroll
  for (int mi = 0; mi < 4; ++mi) {
#pragma unroll
    for (int r = 0; r < 4; ++r) {
      int gm = bm + wm + mi * 16 + quad * 4 + r;
      if (gm >= M) continue;
#pragma unroll
      for (int ni = 0; ni < 5; ++ni) {
        int gn = colbase + wn + ni * 16 + lr;
        out[(size_t)gm * NPERM + gn] = f2bf(acc[mi][ni][r] + pbv[ni]);
      }
    }
  }
}

// ======================= per-node attention pre-dots (permuted layout) =======================
__global__ __launch_bounds__(256) void k_pre(const ushort* __restrict__ xl,
                                             const ushort* __restrict__ xr,
                                             const float* __restrict__ att,
                                             float* __restrict__ pl,
                                             float* __restrict__ pr, int n) {
  int wave = threadIdx.x >> 6, lane = threadIdx.x & 63;
  int d = blockIdx.x * 4 + wave;
  if (d >= n) return;
  int hgrp = lane >> 4, li = lane & 15;
  int fbase = hgrp * CDIM + li;
  u16x4 a4 = *(const u16x4*)(xl + (size_t)d * NPERM + lane * 4);
  u16x4 b4 = *(const u16x4*)(xr + (size_t)d * NPERM + lane * 4);
  ushort a1 = xl[(size_t)d * NPERM + 256 + lane];
  ushort b1 = xr[(size_t)d * NPERM + 256 + lane];
  float Ta = 0.f, Tb = 0.f;
#pragma unroll
  for (int k = 0; k < 4; ++k) {
    float a = att[fbase + 16 * k];
    Ta = fmaf(bf2f(a4[k]), a, Ta);
    Tb = fmaf(bf2f(b4[k]), a, Tb);
  }
  {
    bool act = li < (CDIM - 64);   // li < 9
    float a = act ? att[fbase + 64] : 0.f;
    Ta = fmaf(bf2f(a1), a, Ta);
    Tb = fmaf(bf2f(b1), a, Tb);
  }
#pragma unroll
  for (int off = 1; off < 16; off <<= 1) {
    Ta += __shfl_xor(Ta, off, 64);
    Tb += __shfl_xor(Tb, off, 64);
  }
  if (li == 0) {
    pl[d * 4 + hgrp] = 0.6f * Ta;
    pr[d * 4 + hgrp] = 0.6f * Tb;
  }
}

// ======================= fused GATv2 attention (unroll-2 pipeline) =======================
__global__ __launch_bounds__(256) void k_agg(const ushort* __restrict__ xl,
                                             const ushort* __restrict__ xr,
                                             const float* __restrict__ pl,
                                             const float* __restrict__ pr,
                                             const int* __restrict__ csr_src,
                                             const int* __restrict__ row_ptr,
                                             const float* __restrict__ att,
                                             const float* __restrict__ bvec,
                                             float* __restrict__ out, int n) {
  int wave = threadIdx.x >> 6, lane = threadIdx.x & 63;
  int d = blockIdx.x * 4 + wave;
  if (d >= n) return;
  int hgrp = lane >> 4, li = lane & 15;
  int start = __builtin_amdgcn_readfirstlane(row_ptr[d]);
  int end = __builtin_amdgcn_readfirstlane(row_ptr[d + 1]);

  int fbase = hgrp * CDIM + li;
  bool act4 = li < (CDIM - 64);
  int fi[SLOTS];
#pragma unroll
  for (int k = 0; k < 4; ++k) fi[k] = fbase + 16 * k;
  fi[4] = act4 ? fbase + 64 : fbase;

  if (start >= end) {                            // isolated node -> bias only
#pragma unroll
    for (int k = 0; k < 4; ++k) out[(size_t)d * HCDIM + fi[k]] = bvec[fi[k]];
    if (act4) out[(size_t)d * HCDIM + fi[4]] = bvec[fi[4]];
    return;
  }

  float xrv[SLOTS], attv[SLOTS], acc[SLOTS] = {};
  {
    u16x4 b4 = *(const u16x4*)(xr + (size_t)d * NPERM + lane * 4);
#pragma unroll
    for (int k = 0; k < 4; ++k) {
      xrv[k] = bf2f(b4[k]);
      attv[k] = 0.4f * att[fi[k]];
    }
    xrv[4] = bf2f(xr[(size_t)d * NPERM + 256 + lane]);
    attv[4] = act4 ? 0.4f * att[fi[4]] : 0.f;
  }
  float prv = pr[d * 4 + hgrp];
  float den = 0.f;
  int deg = end - start;

  // two-slot (a,b) pipeline, 2 edges per iteration
  int sA = __builtin_amdgcn_readfirstlane(csr_src[start]);
  int eB0 = (deg > 1) ? start + 1 : start;
  int sB = __builtin_amdgcn_readfirstlane(csr_src[eB0]);
  u16x4 a4 = *(const u16x4*)(xl + (size_t)sA * NPERM + lane * 4);
  ushort a1 = xl[(size_t)sA * NPERM + 256 + lane];
  float plA = pl[sA * 4 + hgrp];
  u16x4 b4 = *(const u16x4*)(xl + (size_t)sB * NPERM + lane * 4);
  ushort b1 = xl[(size_t)sB * NPERM + 256 + lane];
  float plB = pl[sB * 4 + hgrp];

  for (int e = start; e + 1 < end; e += 2) {
    // prefetch pair (e+2, e+3), clamped
    int p0 = (e + 2 < end) ? e + 2 : end - 1;
    int p1 = (e + 3 < end) ? e + 3 : end - 1;
    int t0 = __builtin_amdgcn_readfirstlane(csr_src[p0]);
    int t1 = __builtin_amdgcn_readfirstlane(csr_src[p1]);
    u16x4 n4a = *(const u16x4*)(xl + (size_t)t0 * NPERM + lane * 4);
    ushort n1a = xl[(size_t)t0 * NPERM + 256 + lane];
    float plN0 = pl[t0 * 4 + hgrp];
    u16x4 n4b = *(const u16x4*)(xl + (size_t)t1 * NPERM + lane * 4);
    ushort n1b = xl[(size_t)t1 * NPERM + 256 + lane];
    float plN1 = pl[t1 * 4 + hgrp];

    float xa[SLOTS] = {bf2f(a4[0]), bf2f(a4[1]), bf2f(a4[2]), bf2f(a4[3]), bf2f(a1)};
    float xb[SLOTS] = {bf2f(b4[0]), bf2f(b4[1]), bf2f(b4[2]), bf2f(b4[3]), bf2f(b1)};
    float Ta = 0.f, Tb = 0.f;
#pragma unroll
    for (int k = 0; k < SLOTS; ++k) {
      Ta = fmaf(fabsf(xa[k] + xrv[k]), attv[k], Ta);
      Tb = fmaf(fabsf(xb[k] + xrv[k]), attv[k], Tb);
    }
    Ta += __shfl_xor(Ta, 1, 64);  Tb += __shfl_xor(Tb, 1, 64);
    Ta += __shfl_xor(Ta, 2, 64);  Tb += __shfl_xor(Tb, 2, 64);
    Ta += __shfl_xor(Ta, 4, 64);  Tb += __shfl_xor(Tb, 4, 64);
    Ta += __shfl_xor(Ta, 8, 64);  Tb += __shfl_xor(Tb, 8, 64);
    float sa_ = fminf(Ta + plA + prv, 60.f);
    float sb_ = fminf(Tb + plB + prv, 60.f);
    float wa = __expf(sa_);
    float wb = __expf(sb_);
    den += wa + wb;
#pragma unroll
    for (int k = 0; k < SLOTS; ++k) {
      acc[k] = fmaf(wa, xa[k], acc[k]);
      acc[k] = fmaf(wb, xb[k], acc[k]);
    }
    a4 = n4a; a1 = n1a; plA = plN0;
    b4 = n4b; b1 = n1b; plB = plN1;
  }

  if (deg & 1) {   // leftover edge sits in the a-slot
    float xa[SLOTS] = {bf2f(a4[0]), bf2f(a4[1]), bf2f(a4[2]), bf2f(a4[3]), bf2f(a1)};
    float Ta = 0.f;
#pragma unroll
    for (int k = 0; k < SLOTS; ++k)
      Ta = fmaf(fabsf(xa[k] + xrv[k]), attv[k], Ta);
    Ta += __shfl_xor(Ta, 1, 64);
    Ta += __shfl_xor(Ta, 2, 64);
    Ta += __shfl_xor(Ta, 4, 64);
    Ta += __shfl_xor(Ta, 8, 64);
    float sa_ = fminf(Ta + plA + prv, 60.f);
    float wa = __expf(sa_);
    den += wa;
#pragma unroll
    for (int k = 0; k < SLOTS; ++k) acc[k] = fmaf(wa, xa[k], acc[k]);
  }

  float inv = 1.f / (den + 1e-16f);
#pragma unroll
  for (int k = 0; k < 4; ++k)
    out[(size_t)d * HCDIM + fi[k]] = fmaf(acc[k], inv, bvec[fi[k]]);
  if (act4)
    out[(size_t)d * HCDIM + fi[4]] = fmaf(acc[4], inv, bvec[fi[4]]);
}

// ======================= BatchNorm =======================
__global__ __launch_bounds__(320) void k_bn_reduce(const float* __restrict__ h,
                                                   float* __restrict__ colsum,
                                                   float* __restrict__ colsq,
                                                   int n, int rows_per_block) {
  int c = threadIdx.x;
  if (c >= HCDIM) return;
  int r0 = blockIdx.x * rows_per_block;
  int r1 = min(r0 + rows_per_block, n);
  float s = 0.f, s2 = 0.f;
  for (int r = r0; r < r1; ++r) {
    float v = h[(size_t)r * HCDIM + c];
    s += v;
    s2 += v * v;
  }
  atomicAdd(&colsum[c], s);
  atomicAdd(&colsq[c], s2);
}

__global__ void k_bn_coef(float* __restrict__ colsum, float* __restrict__ colsq,
                          const float* __restrict__ gamma,
                          const float* __restrict__ beta, float invN) {
  int c = threadIdx.x + blockIdx.x * blockDim.x;
  if (c >= HCDIM) return;
  float mu = colsum[c] * invN;
  float var = colsq[c] * invN - mu * mu;
  float scale = rsqrtf(var + BN_EPS) * gamma[c];
  colsum[c] = scale;
  colsq[c] = beta[c] - mu * scale;
}

__global__ __launch_bounds__(320) void k_bn_apply_bf(
    const float* __restrict__ h, const float* __restrict__ scale,
    const float* __restrict__ shift, ushort* __restrict__ outb, int n) {
  int r = blockIdx.x, c = threadIdx.x;
  if (r >= n) return;
  ushort o = 0;
  if (c < HCDIM) {
    float v = fmaf(h[(size_t)r * HCDIM + c], scale[c], shift[c]);
    v = (v > 0.f) ? v : 0.01f * v;
    o = f2bf(v);
  }
  outb[(size_t)r * KP2 + c] = o;
}

// ======================= fused BN + leaky-relu + classifier =======================
__global__ __launch_bounds__(256) void k_bn_classifier(
    const float* __restrict__ h, const float* __restrict__ scale,
    const float* __restrict__ shift, const float* __restrict__ Wc,
    const float* __restrict__ bc, float* __restrict__ out, int n) {
  int wave = threadIdx.x >> 6, lane = threadIdx.x & 63;
  int r = blockIdx.x * 4 + wave;
  if (r >= n) return;
  float a0 = 0.f, a1 = 0.f;
#pragma unroll
  for (int k = 0; k < SLOTS; ++k) {
    int slot = lane + 64 * k;
    if (slot < HCDIM) {
      float v = fmaf(h[(size_t)r * HCDIM + slot], scale[slot], shift[slot]);
      v = (v > 0.f) ? v : 0.01f * v;
      a0 = fmaf(v, Wc[slot], a0);
      a1 = fmaf(v, Wc[HCDIM + slot], a1);
    }
  }
#pragma unroll
  for (int off = 32; off > 0; off >>= 1) {
    a0 += __shfl_xor(a0, off, 64);
    a1 += __shfl_xor(a1, off, 64);
  }
  if (lane == 0) {
    out[(size_t)2 * r] = a0 + bc[0];
    out[(size_t)2 * r + 1] = a1 + bc[1];
  }
}

// ======================= host launch =======================
extern "C" void kernel_launch(void* const* d_in, const int* in_sizes, int n_in,
                              void* d_out, int out_size, void* d_ws, size_t ws_size,
                              hipStream_t stream) {
  const float* x      = (const float*)d_in[0];
  const int*   eidx   = (const int*)d_in[1];
  const float* Wl1    = (const float*)d_in[2];
  const float* bl1    = (const float*)d_in[3];
  const float* Wr1    = (const float*)d_in[4];
  const float* br1    = (const float*)d_in[5];
  const float* att1   = (const float*)d_in[6];
  const float* b1     = (const float*)d_in[7];
  const float* Wl2    = (const float*)d_in[8];
  const float* bl2    = (const float*)d_in[9];
  const float* Wr2    = (const float*)d_in[10];
  const float* br2    = (const float*)d_in[11];
  const float* att2   = (const float*)d_in[12];
  const float* b2     = (const float*)d_in[13];
  const float* gamma  = (const float*)d_in[14];
  const float* beta   = (const float*)d_in[15];
  const float* Wc     = (const float*)d_in[16];
  const float* bc     = (const float*)d_in[17];
  float* out = (float*)d_out;

  const int FIN = 128;
  const int N = in_sizes[0] / FIN;   // 50000
  const int E = in_sizes[1] / 2;     // 800000
  const int NHC = N * HCDIM;

  const int* src = eidx;
  const int* dst = eidx + E;

  // ---- workspace layout (16B-aligned) ----
  float* h       = (float*)d_ws;                  // N*HCDIM f32
  ushort* xl     = (ushort*)(h + NHC);            // N*320 bf16 (permuted)
  ushort* xr     = xl + (size_t)N * NPERM;        // N*320
  ushort* abuf   = xr + (size_t)N * NPERM;        // N*KP2 bf16 (GEMM A input)
  ushort* wb     = abuf + (size_t)N * KP2;        // 640*KP2 combined Wl|Wr permuted
  float* pb      = (float*)(wb + (size_t)2 * NPERM * KP2);  // 640
  float* pl      = pb + 2 * NPERM;                // N*4
  float* pr      = pl + (size_t)N * NHEAD;        // N*4
  float* colsum  = pr + (size_t)N * NHEAD;        // HCDIM (-> scale)
  float* colsq   = colsum + HCDIM;                // HCDIM (-> shift)
  int* deg       = (int*)(colsq + HCDIM);
  int* row_ptr   = deg + N;                       // N+1
  int* cursor    = row_ptr + N + 1;
  int* bsum      = cursor + N;                    // 256
  int* boff      = bsum + 256;                    // 256
  int* csr_src   = boff + 256;                    // E

  const int G = (N + 255) / 256;
  const int EB = (E + 255) / 256;
  const int AGGB = (N + 3) / 4;

  // ---- CSR build ----
  k_zero_i32<<<G, 256, 0, stream>>>(deg, N);
  k_hist<<<EB, 256, 0, stream>>>(dst, deg, E);
  k_block_sum<<<G, 256, 0, stream>>>(deg, bsum, N);
  k_scan_small<<<1, 256, 0, stream>>>(bsum, boff, G);
  k_scan_final<<<G, 256, 0, stream>>>(deg, boff, row_ptr, cursor, N, E);
  k_csr_fill<<<EB, 256, 0, stream>>>(src, dst, cursor, csr_src, E);

  dim3 gemm_grid(4, (N + 127) / 128);   // column-tile fastest -> A-tile L2/L3 reuse

  // ---- layer 1 ----
  k_cvt_pad<<<(N * FIN + 255) / 256, 256, 0, stream>>>(x, abuf, N, FIN, FIN);
  k_wperm<<<NPERM, FIN, 0, stream>>>(Wl1, bl1, wb, pb, FIN, FIN);
  k_wperm<<<NPERM, FIN, 0, stream>>>(Wr1, br1, wb + (size_t)NPERM * FIN, pb + NPERM,
                                     FIN, FIN);
  k_gemm_mfma<<<gemm_grid, 256, 0, stream>>>(abuf, wb, pb, xl, xr, N, FIN);
  k_pre<<<AGGB, 256, 0, stream>>>(xl, xr, att1, pl, pr, N);
  k_agg<<<AGGB, 256, 0, stream>>>(xl, xr, pl, pr, csr_src, row_ptr, att1, b1, h, N);

  const int RPB = (N + 255) / 256;
  k_zero_f32<<<1, 2 * HCDIM, 0, stream>>>(colsum, 2 * HCDIM);
  k_bn_reduce<<<256, 320, 0, stream>>>(h, colsum, colsq, N, RPB);
  k_bn_coef<<<2, 160, 0, stream>>>(colsum, colsq, gamma, beta, 1.f / (float)N);
  k_bn_apply_bf<<<N, KP2, 0, stream>>>(h, colsum, colsq, abuf, N);

  // ---- layer 2 ----
  k_wperm<<<NPERM, KP2, 0, stream>>>(Wl2, bl2, wb, pb, HCDIM, KP2);
  k_wperm<<<NPERM, KP2, 0, stream>>>(Wr2, br2, wb + (size_t)NPERM * KP2, pb + NPERM,
                                     HCDIM, KP2);
  k_gemm_mfma<<<gemm_grid, 256, 0, stream>>>(abuf, wb, pb, xl, xr, N, KP2);
  k_pre<<<AGGB, 256, 0, stream>>>(xl, xr, att2, pl, pr, N);
  k_agg<<<AGGB, 256, 0, stream>>>(xl, xr, pl, pr, csr_src, row_ptr, att2, b2, h, N);

  k_zero_f32<<<1, 2 * HCDIM, 0, stream>>>(colsum, 2 * HCDIM);
  k_bn_reduce<<<256, 320, 0, stream>>>(h, colsum, colsq, N, RPB);
  k_bn_coef<<<2, 160, 0, stream>>>(colsum, colsq, gamma, beta, 1.f / (float)N);

  // ---- fused BN + classifier ----
  k_bn_classifier<<<AGGB, 256, 0, stream>>>(h, colsum, colsq, Wc, bc, out, N);
}

// Round 7
// 641.379 us; speedup vs baseline: 2.4231x; 1.0528x over previous
//
#include <hip/hip_runtime.h>

#define HCDIM 292
#define NHEAD 4
#define CDIM 73
#define SLOTS 5
#define NPERM 320
#define BN_EPS 1e-5f

using u16x8 = __attribute__((ext_vector_type(8))) unsigned short;
using s16x8 = __attribute__((ext_vector_type(8))) short;   // 8 bf16 MFMA frag
using f32x4 = __attribute__((ext_vector_type(4))) float;   // MFMA acc
using u16x4 = __attribute__((ext_vector_type(4))) unsigned short;

__device__ inline ushort f2bf(float f) {       // RTN-even fp32 -> bf16
  unsigned int u = __float_as_uint(f);
  u += 0x7FFFu + ((u >> 16) & 1u);
  return (ushort)(u >> 16);
}
__device__ inline float bf2f(ushort v) {
  return __uint_as_float(((unsigned int)v) << 16);
}

// permuted slot p -> original feature index (h*73+c); valid=false for 28 dead slots
__device__ inline int perm2feat(int p, bool& valid) {
  int h, c;
  if (p < 256) {
    h = p >> 6;
    c = ((p & 3) << 4) | ((p >> 2) & 15);
    valid = true;
  } else {
    int q = p - 256;
    h = q >> 4;
    c = 64 + (q & 15);
    valid = (q & 15) < (CDIM - 64);
  }
  return h * CDIM + c;
}

// ======================= utility =======================
__global__ void k_zero_i32(int* __restrict__ p, int n) {
  int i = blockIdx.x * blockDim.x + threadIdx.x;
  if (i < n) p[i] = 0;
}
__global__ void k_zero_f32(float* __restrict__ p, int n) {
  int i = blockIdx.x * blockDim.x + threadIdx.x;
  if (i < n) p[i] = 0.f;
}

// fp32 [rows,K] -> bf16 flat convert (layer-1 A staging)
__global__ void k_cvt(const float* __restrict__ src, ushort* __restrict__ dst,
                      int total) {
  int i = blockIdx.x * blockDim.x + threadIdx.x;
  if (i < total) dst[i] = f2bf(src[i]);
}

// weight prep: Wp[p][Kpad] bf16, rows in agg-lane perm; optionally K-cols permuted too.
// dead rows/cols -> 0. pb[p] = bias (dead -> 0).
__global__ void k_wperm(const float* __restrict__ W, const float* __restrict__ b,
                        ushort* __restrict__ Wp, float* __restrict__ pb,
                        int Kin, int Kpad, int kperm) {
  int p = blockIdx.x, t = threadIdx.x;
  bool pv;
  int gn = perm2feat(p, pv);
  int gk = t;
  bool kv = t < Kin;
  if (kperm) { bool v2; gk = perm2feat(t, v2); kv = v2; }
  ushort v = 0;
  if (pv && kv) v = f2bf(W[(size_t)gn * Kin + gk]);
  Wp[(size_t)p * Kpad + t] = v;
  if (t == 0) pb[p] = pv ? b[gn] : 0.f;
}

// permute the small per-feature vectors into agg-lane order (dead -> 0).
// o layout: [att1|b1|att2|b2|gamma|beta|Wc0|Wc1] x 320
__global__ void k_vecperm(const float* __restrict__ att1, const float* __restrict__ b1,
                          const float* __restrict__ att2, const float* __restrict__ b2,
                          const float* __restrict__ gamma, const float* __restrict__ beta,
                          const float* __restrict__ Wc, float* __restrict__ o) {
  int p = threadIdx.x, w = blockIdx.x;
  bool pv;
  int gn = perm2feat(p, pv);
  const float* src;
  switch (w) {
    case 0: src = att1; break;
    case 1: src = b1; break;
    case 2: src = att2; break;
    case 3: src = b2; break;
    case 4: src = gamma; break;
    case 5: src = beta; break;
    case 6: src = Wc; break;
    default: src = Wc + HCDIM; break;
  }
  o[w * NPERM + p] = pv ? src[gn] : 0.f;
}

// ======================= CSR build =======================
__global__ void k_hist(const int* __restrict__ dst, int* __restrict__ deg, int E) {
  int i = blockIdx.x * blockDim.x + threadIdx.x;
  if (i < E) atomicAdd(&deg[dst[i]], 1);
}

__global__ __launch_bounds__(256) void k_block_sum(const int* __restrict__ deg,
                                                   int* __restrict__ bsum, int n) {
  __shared__ int s[256];
  int i = blockIdx.x * 256 + threadIdx.x;
  s[threadIdx.x] = (i < n) ? deg[i] : 0;
  __syncthreads();
  for (int off = 128; off > 0; off >>= 1) {
    if (threadIdx.x < off) s[threadIdx.x] += s[threadIdx.x + off];
    __syncthreads();
  }
  if (threadIdx.x == 0) bsum[blockIdx.x] = s[0];
}

__global__ __launch_bounds__(256) void k_scan_small(const int* __restrict__ bsum,
                                                    int* __restrict__ boff, int G) {
  __shared__ int s[256];
  int t = threadIdx.x;
  int v = (t < G) ? bsum[t] : 0;
  s[t] = v;
  __syncthreads();
  for (int off = 1; off < 256; off <<= 1) {
    int tv = (t >= off) ? s[t - off] : 0;
    __syncthreads();
    s[t] += tv;
    __syncthreads();
  }
  if (t < G) boff[t] = s[t] - v;
}

__global__ __launch_bounds__(256) void k_scan_final(const int* __restrict__ deg,
                                                    const int* __restrict__ boff,
                                                    int* __restrict__ row_ptr,
                                                    int* __restrict__ cursor,
                                                    int n, int E) {
  __shared__ int s[256];
  int t = threadIdx.x;
  int i = blockIdx.x * 256 + t;
  int v = (i < n) ? deg[i] : 0;
  s[t] = v;
  __syncthreads();
  for (int off = 1; off < 256; off <<= 1) {
    int tv = (t >= off) ? s[t - off] : 0;
    __syncthreads();
    s[t] += tv;
    __syncthreads();
  }
  if (i < n) {
    int rp = boff[blockIdx.x] + s[t] - v;
    row_ptr[i] = rp;
    cursor[i] = rp;
  }
  if (i == 0) row_ptr[n] = E;
}

__global__ void k_csr_fill(const int* __restrict__ srcs, const int* __restrict__ dsts,
                           int* __restrict__ cursor, int* __restrict__ csr_src, int E) {
  int i = blockIdx.x * blockDim.x + threadIdx.x;
  if (i < E) {
    int pos = atomicAdd(&cursor[dsts[i]], 1);
    csr_src[pos] = srcs[i];
  }
}

// ======================= direct-global MFMA GEMM (no LDS, no barriers) =======================
// out{xl,xr}[M][320] bf16 = A[M,KS] @ Wb[640,KS]^T + pb. Weights are 0.4 MB -> L2-resident.
// Each frag load = 16 rows x 64B full cachelines. 1-D grid XCD-grouped: the 4 column-tiles
// of one m-tile share b%8 (same XCD) -> A-tile L2 reuse. K compile-time -> full unroll.
template <int KS>
__global__ __launch_bounds__(256) void k_gemm_direct(
    const ushort* __restrict__ A, const ushort* __restrict__ Wb,
    const float* __restrict__ pb, ushort* __restrict__ o0,
    ushort* __restrict__ o1, int M, int mt) {
  int b = blockIdx.x;
  int x = b & 7, g = b >> 3;
  int ct = g & 3, mq = g >> 2;
  int m = mq * 8 + x;
  if (m >= mt) return;
  const int bm = m * 128;
  ushort* out = (ct < 2) ? o0 : o1;
  const int colbase = (ct & 1) * 160;
  const int wrow0 = ct * 160;
  const int tid = threadIdx.x;
  const int wave = tid >> 6, lane = tid & 63;
  const int quad = lane >> 4, lr = lane & 15;
  const int wm = (wave & 1) * 64, wn = (wave >> 1) * 80;

  f32x4 acc[4][5] = {};

  const ushort* Arow[4];
  const ushort* Brow[5];
#pragma unroll
  for (int i = 0; i < 4; ++i) {
    int ar = bm + wm + i * 16 + lr;
    if (ar >= M) ar = M - 1;       // clamped; those D rows are discarded
    Arow[i] = A + (size_t)ar * KS;
  }
#pragma unroll
  for (int i = 0; i < 5; ++i)
    Brow[i] = Wb + (size_t)(wrow0 + wn + i * 16 + lr) * KS;

#pragma unroll
  for (int k0 = 0; k0 < KS; k0 += 32) {
    s16x8 af[4], bf[5];
#pragma unroll
    for (int i = 0; i < 4; ++i)
      af[i] = *(const s16x8*)(Arow[i] + k0 + quad * 8);
#pragma unroll
    for (int i = 0; i < 5; ++i)
      bf[i] = *(const s16x8*)(Brow[i] + k0 + quad * 8);
#pragma unroll
    for (int mi = 0; mi < 4; ++mi)
#pragma unroll
      for (int ni = 0; ni < 5; ++ni)
        acc[mi][ni] = __builtin_amdgcn_mfma_f32_16x16x32_bf16(af[mi], bf[ni],
                                                              acc[mi][ni], 0, 0, 0);
  }

  float pbv[5];
#pragma unroll
  for (int ni = 0; ni < 5; ++ni) pbv[ni] = pb[wrow0 + wn + ni * 16 + lr];

  // C/D layout: col = lane&15, row = quad*4 + reg
#pragma unroll
  for (int mi = 0; mi < 4; ++mi) {
#pragma unroll
    for (int r = 0; r < 4; ++r) {
      int gm = bm + wm + mi * 16 + quad * 4 + r;
      if (gm >= M) continue;
#pragma unroll
      for (int ni = 0; ni < 5; ++ni) {
        int gn = colbase + wn + ni * 16 + lr;
        out[(size_t)gm * NPERM + gn] = f2bf(acc[mi][ni][r] + pbv[ni]);
      }
    }
  }
}

// ======================= per-node pl (xl attention pre-dot) =======================
__global__ __launch_bounds__(256) void k_pre(const ushort* __restrict__ xl,
                                             const float* __restrict__ attp,
                                             float* __restrict__ pl, int n) {
  int wave = threadIdx.x >> 6, lane = threadIdx.x & 63;
  int d = blockIdx.x * 4 + wave;
  if (d >= n) return;
  int hgrp = lane >> 4, li = lane & 15;
  u16x4 a4 = *(const u16x4*)(xl + (size_t)d * NPERM + lane * 4);
  ushort a1 = xl[(size_t)d * NPERM + 256 + lane];
  float Ta = 0.f;
#pragma unroll
  for (int k = 0; k < 4; ++k) Ta = fmaf(bf2f(a4[k]), attp[lane * 4 + k], Ta);
  Ta = fmaf(bf2f(a1), attp[256 + lane], Ta);
#pragma unroll
  for (int off = 1; off < 16; off <<= 1) Ta += __shfl_xor(Ta, off, 64);
  if (li == 0) pl[d * 4 + hgrp] = 0.6f * Ta;
}

// ======================= fused GATv2 attention (permuted-native, bf16 out) =======================
__global__ __launch_bounds__(256) void k_agg(const ushort* __restrict__ xl,
                                             const ushort* __restrict__ xr,
                                             const float* __restrict__ pl,
                                             const int* __restrict__ csr_src,
                                             const int* __restrict__ row_ptr,
                                             const float* __restrict__ attp,
                                             const float* __restrict__ bp,
                                             ushort* __restrict__ out, int n) {
  int wave = threadIdx.x >> 6, lane = threadIdx.x & 63;
  int d = blockIdx.x * 4 + wave;
  if (d >= n) return;
  int hgrp = lane >> 4;
  int start = __builtin_amdgcn_readfirstlane(row_ptr[d]);
  int end = __builtin_amdgcn_readfirstlane(row_ptr[d + 1]);

  float bpv[SLOTS];
#pragma unroll
  for (int k = 0; k < 4; ++k) bpv[k] = bp[lane * 4 + k];
  bpv[4] = bp[256 + lane];

  if (start >= end) {                      // isolated node -> bias only
    u16x4 o4;
#pragma unroll
    for (int k = 0; k < 4; ++k) o4[k] = f2bf(bpv[k]);
    *(u16x4*)(out + (size_t)d * NPERM + lane * 4) = o4;
    out[(size_t)d * NPERM + 256 + lane] = f2bf(bpv[4]);
    return;
  }

  float xrv[SLOTS], attv[SLOTS], acc[SLOTS] = {};
  {
    u16x4 r4 = *(const u16x4*)(xr + (size_t)d * NPERM + lane * 4);
#pragma unroll
    for (int k = 0; k < 4; ++k) {
      xrv[k] = bf2f(r4[k]);
      attv[k] = 0.4f * attp[lane * 4 + k];
    }
    xrv[4] = bf2f(xr[(size_t)d * NPERM + 256 + lane]);
    attv[4] = 0.4f * attp[256 + lane];
  }
  // prv computed locally: pr = 0.6*sum(xr*att) = 1.5*sum(xrv*attv)
  float Tb = 0.f;
#pragma unroll
  for (int k = 0; k < SLOTS; ++k) Tb = fmaf(xrv[k], attv[k], Tb);
  Tb += __shfl_xor(Tb, 1, 64);
  Tb += __shfl_xor(Tb, 2, 64);
  Tb += __shfl_xor(Tb, 4, 64);
  Tb += __shfl_xor(Tb, 8, 64);
  float prv = 1.5f * Tb;
  float den = 0.f;
  int dg = end - start;

  // two-slot unroll-2 pipeline
  int sA = __builtin_amdgcn_readfirstlane(csr_src[start]);
  int eB0 = (dg > 1) ? start + 1 : start;
  int sB = __builtin_amdgcn_readfirstlane(csr_src[eB0]);
  u16x4 a4 = *(const u16x4*)(xl + (size_t)sA * NPERM + lane * 4);
  ushort a1 = xl[(size_t)sA * NPERM + 256 + lane];
  float plA = pl[sA * 4 + hgrp];
  u16x4 b4 = *(const u16x4*)(xl + (size_t)sB * NPERM + lane * 4);
  ushort b1 = xl[(size_t)sB * NPERM + 256 + lane];
  float plB = pl[sB * 4 + hgrp];

  for (int e = start; e + 1 < end; e += 2) {
    int p0 = (e + 2 < end) ? e + 2 : end - 1;
    int p1 = (e + 3 < end) ? e + 3 : end - 1;
    int t0 = __builtin_amdgcn_readfirstlane(csr_src[p0]);
    int t1 = __builtin_amdgcn_readfirstlane(csr_src[p1]);
    u16x4 n4a = *(const u16x4*)(xl + (size_t)t0 * NPERM + lane * 4);
    ushort n1a = xl[(size_t)t0 * NPERM + 256 + lane];
    float plN0 = pl[t0 * 4 + hgrp];
    u16x4 n4b = *(const u16x4*)(xl + (size_t)t1 * NPERM + lane * 4);
    ushort n1b = xl[(size_t)t1 * NPERM + 256 + lane];
    float plN1 = pl[t1 * 4 + hgrp];

    float xa[SLOTS] = {bf2f(a4[0]), bf2f(a4[1]), bf2f(a4[2]), bf2f(a4[3]), bf2f(a1)};
    float xb[SLOTS] = {bf2f(b4[0]), bf2f(b4[1]), bf2f(b4[2]), bf2f(b4[3]), bf2f(b1)};
    float Ta = 0.f, Tc = 0.f;
#pragma unroll
    for (int k = 0; k < SLOTS; ++k) {
      Ta = fmaf(fabsf(xa[k] + xrv[k]), attv[k], Ta);
      Tc = fmaf(fabsf(xb[k] + xrv[k]), attv[k], Tc);
    }
    Ta += __shfl_xor(Ta, 1, 64);  Tc += __shfl_xor(Tc, 1, 64);
    Ta += __shfl_xor(Ta, 2, 64);  Tc += __shfl_xor(Tc, 2, 64);
    Ta += __shfl_xor(Ta, 4, 64);  Tc += __shfl_xor(Tc, 4, 64);
    Ta += __shfl_xor(Ta, 8, 64);  Tc += __shfl_xor(Tc, 8, 64);
    float sa_ = fminf(Ta + plA + prv, 60.f);
    float sb_ = fminf(Tc + plB + prv, 60.f);
    float wa = __expf(sa_);
    float wb = __expf(sb_);
    den += wa + wb;
#pragma unroll
    for (int k = 0; k < SLOTS; ++k) {
      acc[k] = fmaf(wa, xa[k], acc[k]);
      acc[k] = fmaf(wb, xb[k], acc[k]);
    }
    a4 = n4a; a1 = n1a; plA = plN0;
    b4 = n4b; b1 = n1b; plB = plN1;
  }

  if (dg & 1) {
    float xa[SLOTS] = {bf2f(a4[0]), bf2f(a4[1]), bf2f(a4[2]), bf2f(a4[3]), bf2f(a1)};
    float Ta = 0.f;
#pragma unroll
    for (int k = 0; k < SLOTS; ++k)
      Ta = fmaf(fabsf(xa[k] + xrv[k]), attv[k], Ta);
    Ta += __shfl_xor(Ta, 1, 64);
    Ta += __shfl_xor(Ta, 2, 64);
    Ta += __shfl_xor(Ta, 4, 64);
    Ta += __shfl_xor(Ta, 8, 64);
    float wa = __expf(fminf(Ta + plA + prv, 60.f));
    den += wa;
#pragma unroll
    for (int k = 0; k < SLOTS; ++k) acc[k] = fmaf(wa, xa[k], acc[k]);
  }

  float inv = 1.f / (den + 1e-16f);
  u16x4 o4;
#pragma unroll
  for (int k = 0; k < 4; ++k) o4[k] = f2bf(fmaf(acc[k], inv, bpv[k]));
  *(u16x4*)(out + (size_t)d * NPERM + lane * 4) = o4;
  out[(size_t)d * NPERM + 256 + lane] = f2bf(fmaf(acc[4], inv, bpv[4]));
}

// ======================= BatchNorm (permuted bf16 h) =======================
__global__ __launch_bounds__(320) void k_bn_reduce(const ushort* __restrict__ h,
                                                   float* __restrict__ colsum,
                                                   float* __restrict__ colsq,
                                                   int n, int rows_per_block) {
  int c = threadIdx.x;
  int r0 = blockIdx.x * rows_per_block;
  int r1 = min(r0 + rows_per_block, n);
  float s = 0.f, s2 = 0.f;
  for (int r = r0; r < r1; ++r) {
    float v = bf2f(h[(size_t)r * NPERM + c]);
    s += v;
    s2 += v * v;
  }
  atomicAdd(&colsum[c], s);
  atomicAdd(&colsq[c], s2);
}

// colsum/colsq -> scale/shift in place (permuted gamma/beta; dead cols -> 0/0)
__global__ void k_bn_coef(float* __restrict__ colsum, float* __restrict__ colsq,
                          const float* __restrict__ gp, const float* __restrict__ bp,
                          float invN) {
  int c = threadIdx.x + blockIdx.x * blockDim.x;
  if (c >= NPERM) return;
  float mu = colsum[c] * invN;
  float var = colsq[c] * invN - mu * mu;
  float scale = rsqrtf(var + BN_EPS) * gp[c];
  colsum[c] = scale;
  colsq[c] = bp[c] - mu * scale;
}

// BN + leaky-relu: h bf16 -> abuf bf16 (layer-2 GEMM A), 8-wide vectors
__global__ void k_bn_apply_bf(const ushort* __restrict__ h,
                              const float* __restrict__ scale,
                              const float* __restrict__ shift,
                              ushort* __restrict__ outb, int total8) {
  int i = blockIdx.x * blockDim.x + threadIdx.x;
  if (i >= total8) return;
  int cg = i - (i / 40) * 40;   // (i % 40) col-group of 8 within the 320 row
  u16x8 v = *(const u16x8*)(h + (size_t)i * 8);
  u16x8 o;
#pragma unroll
  for (int k = 0; k < 8; ++k) {
    int c = cg * 8 + k;
    float f = fmaf(bf2f(v[k]), scale[c], shift[c]);
    f = (f > 0.f) ? f : 0.01f * f;
    o[k] = f2bf(f);
  }
  *(u16x8*)(outb + (size_t)i * 8) = o;
}

// ======================= fused BN + leaky-relu + classifier =======================
__global__ __launch_bounds__(256) void k_bn_classifier(
    const ushort* __restrict__ h, const float* __restrict__ scale,
    const float* __restrict__ shift, const float* __restrict__ wc0,
    const float* __restrict__ wc1, const float* __restrict__ bc,
    float* __restrict__ out, int n) {
  int wave = threadIdx.x >> 6, lane = threadIdx.x & 63;
  int r = blockIdx.x * 4 + wave;
  if (r >= n) return;
  float a0 = 0.f, a1 = 0.f;
#pragma unroll
  for (int k = 0; k < SLOTS; ++k) {
    int slot = lane + 64 * k;
    float v = fmaf(bf2f(h[(size_t)r * NPERM + slot]), scale[slot], shift[slot]);
    v = (v > 0.f) ? v : 0.01f * v;
    a0 = fmaf(v, wc0[slot], a0);
    a1 = fmaf(v, wc1[slot], a1);
  }
#pragma unroll
  for (int off = 32; off > 0; off >>= 1) {
    a0 += __shfl_xor(a0, off, 64);
    a1 += __shfl_xor(a1, off, 64);
  }
  if (lane == 0) {
    out[(size_t)2 * r] = a0 + bc[0];
    out[(size_t)2 * r + 1] = a1 + bc[1];
  }
}

// ======================= host launch =======================
extern "C" void kernel_launch(void* const* d_in, const int* in_sizes, int n_in,
                              void* d_out, int out_size, void* d_ws, size_t ws_size,
                              hipStream_t stream) {
  const float* x      = (const float*)d_in[0];
  const int*   eidx   = (const int*)d_in[1];
  const float* Wl1    = (const float*)d_in[2];
  const float* bl1    = (const float*)d_in[3];
  const float* Wr1    = (const float*)d_in[4];
  const float* br1    = (const float*)d_in[5];
  const float* att1   = (const float*)d_in[6];
  const float* b1     = (const float*)d_in[7];
  const float* Wl2    = (const float*)d_in[8];
  const float* bl2    = (const float*)d_in[9];
  const float* Wr2    = (const float*)d_in[10];
  const float* br2    = (const float*)d_in[11];
  const float* att2   = (const float*)d_in[12];
  const float* b2     = (const float*)d_in[13];
  const float* gamma  = (const float*)d_in[14];
  const float* beta   = (const float*)d_in[15];
  const float* Wc     = (const float*)d_in[16];
  const float* bc     = (const float*)d_in[17];
  float* out = (float*)d_out;

  const int FIN = 128;
  const int N = in_sizes[0] / FIN;   // 50000
  const int E = in_sizes[1] / 2;     // 800000

  const int* src = eidx;
  const int* dst = eidx + E;

  // ---- workspace layout (16B-aligned) ----
  ushort* h      = (ushort*)d_ws;                 // N*320 bf16 permuted
  ushort* xl     = h + (size_t)N * NPERM;         // N*320
  ushort* xr     = xl + (size_t)N * NPERM;        // N*320
  ushort* abuf   = xr + (size_t)N * NPERM;        // N*320 (layer-1 uses first N*128)
  ushort* wb     = abuf + (size_t)N * NPERM;      // 640*320 combined Wl|Wr
  float* pb      = (float*)(wb + (size_t)2 * NPERM * NPERM);  // 640
  float* vecp    = pb + 2 * NPERM;                // 8*320
  float* pl      = vecp + 8 * NPERM;              // N*4
  float* colsum  = pl + (size_t)N * NHEAD;        // 320 (-> scale)
  float* colsq   = colsum + NPERM;                // 320 (-> shift)
  int* deg       = (int*)(colsq + NPERM);
  int* row_ptr   = deg + N;                       // N+1
  int* cursor    = row_ptr + N + 1;
  int* bsum      = cursor + N;                    // 256
  int* boff      = bsum + 256;                    // 256
  int* csr_src   = boff + 256;                    // E

  const int G = (N + 255) / 256;
  const int EB = (E + 255) / 256;
  const int AGGB = (N + 3) / 4;
  const int mt = (N + 127) / 128;                 // 391 m-tiles
  const int GEMMB = 8 * 4 * ((mt + 7) / 8);       // XCD-grouped 1-D grid

  const float* att1p = vecp;
  const float* b1p   = vecp + NPERM;
  const float* att2p = vecp + 2 * NPERM;
  const float* b2p   = vecp + 3 * NPERM;
  const float* gp    = vecp + 4 * NPERM;
  const float* btp   = vecp + 5 * NPERM;
  const float* wc0   = vecp + 6 * NPERM;
  const float* wc1   = vecp + 7 * NPERM;

  // ---- CSR build ----
  k_zero_i32<<<G, 256, 0, stream>>>(deg, N);
  k_hist<<<EB, 256, 0, stream>>>(dst, deg, E);
  k_block_sum<<<G, 256, 0, stream>>>(deg, bsum, N);
  k_scan_small<<<1, 256, 0, stream>>>(bsum, boff, G);
  k_scan_final<<<G, 256, 0, stream>>>(deg, boff, row_ptr, cursor, N, E);
  k_csr_fill<<<EB, 256, 0, stream>>>(src, dst, cursor, csr_src, E);

  k_vecperm<<<8, NPERM, 0, stream>>>(att1, b1, att2, b2, gamma, beta, Wc, vecp);

  // ---- layer 1 ----
  k_cvt<<<(N * FIN + 255) / 256, 256, 0, stream>>>(x, abuf, N * FIN);
  k_wperm<<<NPERM, FIN, 0, stream>>>(Wl1, bl1, wb, pb, FIN, FIN, 0);
  k_wperm<<<NPERM, FIN, 0, stream>>>(Wr1, br1, wb + (size_t)NPERM * FIN, pb + NPERM,
                                     FIN, FIN, 0);
  k_gemm_direct<FIN><<<GEMMB, 256, 0, stream>>>(abuf, wb, pb, xl, xr, N, mt);
  k_pre<<<AGGB, 256, 0, stream>>>(xl, att1p, pl, N);
  k_agg<<<AGGB, 256, 0, stream>>>(xl, xr, pl, csr_src, row_ptr, att1p, b1p, h, N);

  const int RPB = (N + 255) / 256;
  k_zero_f32<<<1, 2 * NPERM, 0, stream>>>(colsum, 2 * NPERM);
  k_bn_reduce<<<256, NPERM, 0, stream>>>(h, colsum, colsq, N, RPB);
  k_bn_coef<<<2, 160, 0, stream>>>(colsum, colsq, gp, btp, 1.f / (float)N);
  k_bn_apply_bf<<<(N * 40 + 255) / 256, 256, 0, stream>>>(h, colsum, colsq, abuf,
                                                          N * 40);

  // ---- layer 2 (K permuted to match permuted-native abuf) ----
  k_wperm<<<NPERM, NPERM, 0, stream>>>(Wl2, bl2, wb, pb, HCDIM, NPERM, 1);
  k_wperm<<<NPERM, NPERM, 0, stream>>>(Wr2, br2, wb + (size_t)NPERM * NPERM,
                                       pb + NPERM, HCDIM, NPERM, 1);
  k_gemm_direct<NPERM><<<GEMMB, 256, 0, stream>>>(abuf, wb, pb, xl, xr, N, mt);
  k_pre<<<AGGB, 256, 0, stream>>>(xl, att2p, pl, N);
  k_agg<<<AGGB, 256, 0, stream>>>(xl, xr, pl, csr_src, row_ptr, att2p, b2p, h, N);

  k_zero_f32<<<1, 2 * NPERM, 0, stream>>>(colsum, 2 * NPERM);
  k_bn_reduce<<<256, NPERM, 0, stream>>>(h, colsum, colsq, N, RPB);
  k_bn_coef<<<2, 160, 0, stream>>>(colsum, colsq, gp, btp, 1.f / (float)N);

  // ---- fused BN + classifier ----
  k_bn_classifier<<<AGGB, 256, 0, stream>>>(h, colsum, colsq, wc0, wc1, bc, out, N);
}